// Round 4
// baseline (4063.229 us; speedup 1.0000x reference)
//
#include <hip/hip_runtime.h>
#include <cstdint>
#include <cstddef>

#define B_ 16
#define D_ 128
#define T_ 4500
#define N_ (B_*T_)      // 72000
#define K_ 1024
#define L_ 8
#define NRB 2250        // 32-row blocks
#define NRB_PAD 2252
#define DELTA 1.5e-4f

typedef __bf16 bf16x8 __attribute__((ext_vector_type(8)));
typedef float f32x16 __attribute__((ext_vector_type(16)));

#define GLOBAL_AS __attribute__((address_space(1)))
#define LDS_AS    __attribute__((address_space(3)))

// ---------------- helpers ----------------
// RNE f32 -> bf16 (values are tame: no NaN/Inf handling needed)
__device__ __forceinline__ unsigned short f2bf(float x) {
  unsigned u = __float_as_uint(x);
  return (unsigned short)((u + 0x7FFFu + ((u >> 16) & 1u)) >> 16);
}
// split 8 f32 into bf16 hi / bf16 lo packed as uint4 each
__device__ __forceinline__ void pack_split(const float* rn, uint4& H, uint4& L) {
  unsigned hw[8], lw[8];
#pragma unroll
  for (int i = 0; i < 8; ++i) {
    unsigned short h = f2bf(rn[i]);
    float hf = __uint_as_float(((unsigned)h) << 16);
    unsigned short lo = f2bf(__fsub_rn(rn[i], hf));
    hw[i] = h; lw[i] = lo;
  }
  H.x = hw[0] | (hw[1] << 16); H.y = hw[2] | (hw[3] << 16);
  H.z = hw[4] | (hw[5] << 16); H.w = hw[6] | (hw[7] << 16);
  L.x = lw[0] | (lw[1] << 16); L.y = lw[2] | (lw[3] << 16);
  L.z = lw[4] | (lw[5] << 16); L.w = lw[6] | (lw[7] << 16);
}

// numpy pairwise_sum (n=128) of fl(x*x): 8 stride-8 sequential chains + tree
__device__ __forceinline__ float pairwise_sq_sum128(const float* __restrict__ x) {
  float r[8];
#pragma unroll
  for (int c = 0; c < 8; ++c) r[c] = __fmul_rn(x[c], x[c]);
#pragma unroll
  for (int i = 1; i < 16; ++i)
#pragma unroll
    for (int c = 0; c < 8; ++c)
      r[c] = __fadd_rn(r[c], __fmul_rn(x[8*i + c], x[8*i + c]));
  return __fadd_rn(__fadd_rn(__fadd_rn(r[0], r[1]), __fadd_rn(r[2], r[3])),
                   __fadd_rn(__fadd_rn(r[4], r[5]), __fadd_rn(r[6], r[7])));
}

__device__ __forceinline__ float tree8(const float* rc) {
  return __fadd_rn(__fadd_rn(__fadd_rn(rc[0], rc[1]), __fadd_rn(rc[2], rc[3])),
                   __fadd_rn(__fadd_rn(rc[4], rc[5]), __fadd_rn(rc[6], rc[7])));
}

// ---------------- transpose z [B][D][T] -> R [N][D] ----------------
__global__ __launch_bounds__(256)
void k_transpose_z(const float* __restrict__ z, float* __restrict__ R) {
  __shared__ float tile[32][33];
  const int t0 = blockIdx.x * 32;
  const int d0 = blockIdx.y * 32;
  const int b  = blockIdx.z;
  const int tid = threadIdx.x;
  {
    const int jj = tid & 31; const int ii0 = (tid >> 5) * 4;
#pragma unroll
    for (int r = 0; r < 4; ++r) {
      const int ii = ii0 + r;
      float v = 0.f;
      if (t0 + jj < T_) v = z[((size_t)(b*D_ + d0 + ii))*T_ + t0 + jj];
      tile[ii][jj] = v;
    }
  }
  __syncthreads();
  {
    const int ii = tid & 31; const int jj0 = (tid >> 5) * 4;
#pragma unroll
    for (int r = 0; r < 4; ++r) {
      const int jj = jj0 + r;
      if (t0 + jj < T_)
        R[((size_t)(b*T_ + t0 + jj))*D_ + d0 + ii] = tile[ii][jj];
    }
  }
}

// ---------------- per-code squared norms (numpy pairwise) ----------------
__global__ __launch_bounds__(256)
void k_y2(const float* __restrict__ cb, float* __restrict__ y2f) {
  const int row = blockIdx.x * 256 + threadIdx.x;
  if (row >= L_ * K_) return;
  y2f[row] = pairwise_sq_sum128(&cb[(size_t)row * D_]);
}

// ---------------- codebook -> fragment-ready bf16 hi/lo ----------------
// Bpk[l][colblk(32)][s(8)][p(2)][lane(64)] : uint4 (8 bf16)
// lane: col = colblk*32 + (lane&31), k = 16s + 8*(lane>>5) + 0..7
__global__ __launch_bounds__(256)
void k_prep_b(const float* __restrict__ cb, uint4* __restrict__ Bpk) {
  const int tid = threadIdx.x;
  const int gw = blockIdx.x*4 + (tid >> 6);   // 0..255
  const int l = gw >> 5, cbk = gw & 31;
  const int lane = tid & 63, l31 = lane & 31, lh = lane >> 5;
  const int col = cbk*32 + l31;
  const float* src = cb + ((size_t)l*K_ + col)*D_ + lh*8;
  uint4* dst = Bpk + (size_t)l*32768 + (size_t)cbk*1024;
#pragma unroll
  for (int s = 0; s < 8; ++s) {
    float4 va = *(const float4*)(src + s*16);
    float4 vb = *(const float4*)(src + s*16 + 4);
    float rn[8] = {va.x, va.y, va.z, va.w, vb.x, vb.y, vb.z, vb.w};
    uint4 H, L; pack_split(rn, H, L);
    dst[(2*s+0)*64 + lane] = H;
    dst[(2*s+1)*64 + lane] = L;
  }
}

// ---------------- layer-0 split: R -> Apk(hi/lo) + x2 ----------------
__global__ __launch_bounds__(256)
void k_split0(const float* __restrict__ R, uint4* __restrict__ Apk,
              float* __restrict__ x2) {
  const int tid = threadIdx.x;
  const int rowblk = blockIdx.x*4 + (tid >> 6);
  if (rowblk >= NRB) return;
  const int lane = tid & 63, l31 = lane & 31, lh = lane >> 5;
  const int row = rowblk*32 + l31;
  const float* rr = R + (size_t)row*D_ + lh*8;
  uint4* dst = Apk + (size_t)rowblk*1024;
  float rc[8] = {0,0,0,0,0,0,0,0};
#pragma unroll
  for (int s = 0; s < 8; ++s) {
    float4 va = *(const float4*)(rr + s*16);
    float4 vb = *(const float4*)(rr + s*16 + 4);
    float rn[8] = {va.x, va.y, va.z, va.w, vb.x, vb.y, vb.z, vb.w};
    uint4 H, L; pack_split(rn, H, L);
    dst[(2*s+0)*64 + lane] = H;
    dst[(2*s+1)*64 + lane] = L;
    // numpy pairwise: lane lh=0 owns i=2s (k=16s+c), partner (lh=1) i=2s+1
#pragma unroll
    for (int c = 0; c < 8; ++c) {
      const float sq = __fmul_rn(rn[c], rn[c]);
      const float pv = __shfl_xor(sq, 32);
      rc[c] = __fadd_rn(rc[c], sq);
      rc[c] = __fadd_rn(rc[c], pv);
    }
  }
  if (lh == 0) x2[row] = tree8(rc);
}

// ---------------- MFMA screening: top-2 + candidate flags ----------------
__global__ __launch_bounds__(256, 2)
void k_screen(const uint4* __restrict__ Apk, const uint4* __restrict__ Bpk_l,
              const float* __restrict__ x2, const float* __restrict__ y2l,
              int* __restrict__ codes, int* __restrict__ list, int* __restrict__ cnt)
{
  __shared__ uint4 Bs[2][2048];   // 2 x 32KB
  const int tid = threadIdx.x;
  const int wid = tid >> 6;
  const int lane = tid & 63;
  const int l31 = lane & 31;
  const int lh  = lane >> 5;
  const int rowblk = blockIdx.x*4 + wid;
  const bool rowok = (rowblk < NRB);

  uint4 ah[8], al[8];
  {
    const uint4* ab = Apk + (size_t)rowblk*1024 + lane;
#pragma unroll
    for (int s = 0; s < 8; ++s) {
      ah[s] = ab[s*128];
      al[s] = ab[s*128 + 64];
    }
  }
  float x2r[16];
#pragma unroll
  for (int r = 0; r < 16; ++r)
    x2r[r] = x2[rowblk*32 + (r&3) + 8*(r>>2) + 4*lh];

  float v1[16], v2[16]; int j1[16];
#pragma unroll
  for (int r = 0; r < 16; ++r) { v1[r] = 3.0e38f; v2[r] = 3.0e38f; j1[r] = 0; }

  // stage chunk 0
  {
    const uint4* src = Bpk_l + tid;
    LDS_AS uint4* dst = (LDS_AS uint4*)&Bs[0][tid];
#pragma unroll
    for (int i = 0; i < 8; ++i)
      __builtin_amdgcn_global_load_lds((const GLOBAL_AS void*)(src + i*256),
                                       (LDS_AS void*)(dst + i*256), 16, 0, 0);
  }

  int buf = 0;
  for (int ch = 0; ch < 16; ++ch) {
    __syncthreads();   // compiler drains vmcnt+lgkmcnt before barrier
    if (ch < 15) {
      const uint4* src = Bpk_l + (size_t)(ch+1)*2048 + tid;
      LDS_AS uint4* dst = (LDS_AS uint4*)&Bs[buf^1][tid];
#pragma unroll
      for (int i = 0; i < 8; ++i)
        __builtin_amdgcn_global_load_lds((const GLOBAL_AS void*)(src + i*256),
                                         (LDS_AS void*)(dst + i*256), 16, 0, 0);
    }
    f32x16 acc0, acc1;
#pragma unroll
    for (int r = 0; r < 16; ++r) { acc0[r] = 0.f; acc1[r] = 0.f; }
    const uint4* bb = &Bs[buf][0];
#pragma unroll
    for (int s = 0; s < 8; ++s) {
      bf16x8 Ah = __builtin_bit_cast(bf16x8, ah[s]);
      bf16x8 Al = __builtin_bit_cast(bf16x8, al[s]);
      bf16x8 bh0 = __builtin_bit_cast(bf16x8, bb[(2*s+0)*64 + lane]);
      bf16x8 bl0 = __builtin_bit_cast(bf16x8, bb[(2*s+1)*64 + lane]);
      bf16x8 bh1 = __builtin_bit_cast(bf16x8, bb[(16+2*s)*64 + lane]);
      bf16x8 bl1 = __builtin_bit_cast(bf16x8, bb[(17+2*s)*64 + lane]);
      acc0 = __builtin_amdgcn_mfma_f32_32x32x16_bf16(Ah, bh0, acc0, 0, 0, 0);
      acc1 = __builtin_amdgcn_mfma_f32_32x32x16_bf16(Ah, bh1, acc1, 0, 0, 0);
      acc0 = __builtin_amdgcn_mfma_f32_32x32x16_bf16(Al, bh0, acc0, 0, 0, 0);
      acc1 = __builtin_amdgcn_mfma_f32_32x32x16_bf16(Al, bh1, acc1, 0, 0, 0);
      acc0 = __builtin_amdgcn_mfma_f32_32x32x16_bf16(Ah, bl0, acc0, 0, 0, 0);
      acc1 = __builtin_amdgcn_mfma_f32_32x32x16_bf16(Ah, bl1, acc1, 0, 0, 0);
    }
    const int c0 = ch * 64;
    const float y2a = y2l[c0 + l31];
    const float y2b = y2l[c0 + 32 + l31];
    const int ca = c0 + l31, cbx = c0 + 32 + l31;
#pragma unroll
    for (int r = 0; r < 16; ++r) {
      float dv0 = fmaf(-2.f, acc0[r], __fadd_rn(x2r[r], y2a));
      float dv1 = fmaf(-2.f, acc1[r], __fadd_rn(x2r[r], y2b));
      float na = fminf(dv0, dv1);
      float xb = fmaxf(dv0, dv1);
      int jna = (dv0 <= dv1) ? ca : cbx;
      bool c1 = na < v1[r];
      float v2n = c1 ? fminf(v1[r], xb) : fminf(v2[r], na);
      j1[r] = c1 ? jna : j1[r];
      v1[r] = c1 ? na : v1[r];
      v2[r] = v2n;
    }
    buf ^= 1;   // <-- round-3 bug fix: actually swap the double buffers
  }

  // cross-lane reduce within each 32-lane half (rows differ across halves)
#pragma unroll
  for (int r = 0; r < 16; ++r) {
    float a1 = v1[r]; int ja = j1[r]; float a2 = v2[r];
#pragma unroll
    for (int off = 1; off < 32; off <<= 1) {
      float b1 = __shfl_xor(a1, off);
      int   jb = __shfl_xor(ja, off);
      float b2 = __shfl_xor(a2, off);
      float mx = fmaxf(a1, b1);
      bool sel = (b1 < a1) || (b1 == a1 && jb < ja);
      a1 = sel ? b1 : a1;
      ja = sel ? jb : ja;
      a2 = fminf(fminf(a2, b2), mx);
    }
    if (l31 == 0 && rowok) {
      const int n = rowblk*32 + (r&3) + 8*(r>>2) + 4*lh;
      codes[n] = ja;
      if (a2 - a1 <= DELTA) {
        int p = atomicAdd(cnt, 1);
        list[p] = n;
      }
    }
  }
}

// ---------------- exact f32-chain fixup for flagged rows ----------------
__global__ __launch_bounds__(256)
void k_fixup(const float* __restrict__ R, const float* __restrict__ cbl,
             const float* __restrict__ x2, const float* __restrict__ y2l,
             const int* __restrict__ cnt, const int* __restrict__ list,
             int* __restrict__ codes)
{
  __shared__ float rs[4][128];
  const int tid = threadIdx.x;
  const int wid = tid >> 6, lane = tid & 63;
  const int nw = gridDim.x * 4;
  const int gw = blockIdx.x*4 + wid;
  const int C = *cnt;
  for (int it = gw; it < C; it += nw) {
    const int n = list[it];
    float2 t = *(const float2*)&R[(size_t)n*D_ + lane*2];
    rs[wid][lane*2] = t.x; rs[wid][lane*2+1] = t.y;
    asm volatile("s_waitcnt lgkmcnt(0)" ::: "memory");
    const float x2n = x2[n];
    float acc[16];
#pragma unroll
    for (int q = 0; q < 16; ++q) acc[q] = 0.f;
    for (int k = 0; k < 128; k += 4) {
      float4 rv = *(const float4*)&rs[wid][k];
#pragma unroll
      for (int q = 0; q < 16; ++q) {
        const float4 cv = *(const float4*)&cbl[(size_t)(q*64 + lane)*D_ + k];
        acc[q] = fmaf(rv.x, cv.x, acc[q]);
        acc[q] = fmaf(rv.y, cv.y, acc[q]);
        acc[q] = fmaf(rv.z, cv.z, acc[q]);
        acc[q] = fmaf(rv.w, cv.w, acc[q]);
      }
    }
    float vb = 3.0e38f; int jb = 0;
#pragma unroll
    for (int q = 0; q < 16; ++q) {
      const int j = q*64 + lane;
      float dv = fmaf(-2.f, acc[q], __fadd_rn(x2n, y2l[j]));
      if (dv < vb) { vb = dv; jb = j; }   // j ascends with q: ties keep lower
    }
#pragma unroll
    for (int off = 1; off < 64; off <<= 1) {
      float bv = __shfl_xor(vb, off);
      int   bj = __shfl_xor(jb, off);
      if (bv < vb || (bv == vb && bj < jb)) { vb = bv; jb = bj; }
    }
    if (lane == 0) codes[n] = jb;
    // per-wave rs buffer: ensure this iteration's ds_reads are done before
    // the next iteration's ds_write overwrites rs[wid] (no block barrier —
    // trip counts differ per wave).
    asm volatile("s_waitcnt lgkmcnt(0)" ::: "memory");
  }
}

// ---------------- residual update + split + x2 + loss + codes out ----------------
__global__ __launch_bounds__(256)
void k_update(float* __restrict__ R, const float* __restrict__ cbl,
              const int* __restrict__ codes, uint4* __restrict__ Apk,
              float* __restrict__ x2, float* __restrict__ out_codes,
              float* __restrict__ lossp, int last)
{
  const int tid = threadIdx.x;
  const int rowblk = blockIdx.x*4 + (tid >> 6);
  const int lane = tid & 63, l31 = lane & 31, lh = lane >> 5;
  const bool active = (rowblk < NRB);
  float ss = 0.f;
  if (active) {
    const int row = rowblk*32 + l31;
    const int code = codes[row];
    float* rr = R + (size_t)row*D_ + lh*8;
    const float* cr = cbl + (size_t)code*D_ + lh*8;
    uint4* dst = Apk + (size_t)rowblk*1024;
    float rc[8] = {0,0,0,0,0,0,0,0};
#pragma unroll
    for (int s = 0; s < 8; ++s) {
      float4 xa = *(const float4*)(rr + s*16);
      float4 xb = *(const float4*)(rr + s*16 + 4);
      float4 qa = *(const float4*)(cr + s*16);
      float4 qb = *(const float4*)(cr + s*16 + 4);
      float rn[8];
      rn[0] = __fsub_rn(xa.x, qa.x); rn[1] = __fsub_rn(xa.y, qa.y);
      rn[2] = __fsub_rn(xa.z, qa.z); rn[3] = __fsub_rn(xa.w, qa.w);
      rn[4] = __fsub_rn(xb.x, qb.x); rn[5] = __fsub_rn(xb.y, qb.y);
      rn[6] = __fsub_rn(xb.z, qb.z); rn[7] = __fsub_rn(xb.w, qb.w);
      *(float4*)(rr + s*16)     = make_float4(rn[0], rn[1], rn[2], rn[3]);
      *(float4*)(rr + s*16 + 4) = make_float4(rn[4], rn[5], rn[6], rn[7]);
#pragma unroll
      for (int c = 0; c < 8; ++c) ss = fmaf(rn[c], rn[c], ss);
      if (!last) {
        uint4 H, L; pack_split(rn, H, L);
        dst[(2*s+0)*64 + lane] = H;
        dst[(2*s+1)*64 + lane] = L;
      }
      // numpy pairwise x2: lane lh=0 owns i=2s, partner i=2s+1 (squared!)
#pragma unroll
      for (int c = 0; c < 8; ++c) {
        const float sq = __fmul_rn(rn[c], rn[c]);
        const float pv = __shfl_xor(sq, 32);
        rc[c] = __fadd_rn(rc[c], sq);
        rc[c] = __fadd_rn(rc[c], pv);
      }
    }
    if (lh == 0) {
      if (!last) x2[row] = tree8(rc);
      out_codes[row] = (float)code;
    }
  }
#pragma unroll
  for (int off = 1; off < 64; off <<= 1) ss += __shfl_xor(ss, off);
  if (active && lane == 0) atomicAdd(lossp, ss);
}

// ---------------- finalize ----------------
__global__ __launch_bounds__(256)
void k_finalize_quant(const float* __restrict__ z, const float* __restrict__ R,
                      float* __restrict__ out) {
  __shared__ float tile[32][33];
  const int t0 = blockIdx.x * 32;
  const int d0 = blockIdx.y * 32;
  const int b  = blockIdx.z;
  const int tid = threadIdx.x;
  {
    const int ii = tid & 31; const int jj0 = (tid >> 5) * 4;
#pragma unroll
    for (int r = 0; r < 4; ++r) {
      const int jj = jj0 + r;
      tile[ii][jj] = (t0 + jj < T_) ? R[((size_t)(b*T_ + t0 + jj))*D_ + d0 + ii] : 0.f;
    }
  }
  __syncthreads();
  {
    const int jj = tid & 31; const int ii0 = (tid >> 5) * 4;
#pragma unroll
    for (int r = 0; r < 4; ++r) {
      const int ii = ii0 + r;
      if (t0 + jj < T_) {
        const size_t gi = ((size_t)(b*D_ + d0 + ii))*T_ + t0 + jj;
        out[gi] = __fsub_rn(z[gi], tile[ii][jj]);
      }
    }
  }
}

__global__ void k_finalize_loss(const float* __restrict__ lossp, float* __restrict__ out2) {
  const float lv = (float)((double)lossp[0] / (double)((size_t)N_ * D_));
  out2[0] = lv;
  out2[1] = lv;
}

// ---------------- host launch ----------------
extern "C" void kernel_launch(void* const* d_in, const int* in_sizes, int n_in,
                              void* d_out, int out_size, void* d_ws, size_t ws_size,
                              hipStream_t stream) {
  const float* z  = (const float*)d_in[0];
  const float* cb = (const float*)d_in[1];
  float* out = (float*)d_out;

  char* ws = (char*)d_ws;
  const size_t OFF_R     = 0;                                   // 36,864,000
  const size_t OFF_APK   = OFF_R + (size_t)N_ * D_ * 4;         // + 36,896,768
  const size_t OFF_BPK   = OFF_APK + (size_t)NRB_PAD * 16384;   // + 4,194,304
  const size_t OFF_Y2    = OFF_BPK + (size_t)L_ * 32768 * 16;   // + 32,768
  const size_t OFF_X2    = OFF_Y2 + (size_t)L_ * K_ * 4;        // + 288,256
  const size_t OFF_CODES = OFF_X2 + (size_t)NRB_PAD * 32 * 4;   // + 288,000
  const size_t OFF_LIST  = OFF_CODES + (size_t)N_ * 4;          // + 288,000
  const size_t OFF_CTR   = OFF_LIST + (size_t)N_ * 4;           // 8 ints + 1 float

  float* R     = (float*)(ws + OFF_R);
  uint4* Apk   = (uint4*)(ws + OFF_APK);
  uint4* Bpk   = (uint4*)(ws + OFF_BPK);
  float* y2f   = (float*)(ws + OFF_Y2);
  float* x2    = (float*)(ws + OFF_X2);
  int*   codes = (int*)(ws + OFF_CODES);
  int*   list  = (int*)(ws + OFF_LIST);
  int*   ctrs  = (int*)(ws + OFF_CTR);
  float* lossp = (float*)(ws + OFF_CTR + 32);

  hipMemsetAsync(ws + OFF_CTR, 0, 36, stream);

  k_transpose_z<<<dim3((T_ + 31)/32, D_/32, B_), 256, 0, stream>>>(z, R);
  k_y2<<<(L_ * K_)/256, 256, 0, stream>>>(cb, y2f);
  k_prep_b<<<64, 256, 0, stream>>>(cb, Bpk);
  k_split0<<<563, 256, 0, stream>>>(R, Apk, x2);

  for (int l = 0; l < L_; ++l) {
    k_screen<<<563, 256, 0, stream>>>(
        Apk, Bpk + (size_t)l * 32768, x2, y2f + (size_t)l * K_,
        codes, list, ctrs + l);
    k_fixup<<<563, 256, 0, stream>>>(
        R, cb + (size_t)l * K_ * D_, x2, y2f + (size_t)l * K_,
        ctrs + l, list, codes);
    k_update<<<563, 256, 0, stream>>>(
        R, cb + (size_t)l * K_ * D_, codes, Apk, x2,
        out + (size_t)N_ * D_ + (size_t)l * N_, lossp, (l == L_ - 1) ? 1 : 0);
  }

  k_finalize_quant<<<dim3((T_ + 31)/32, D_/32, B_), 256, 0, stream>>>(z, R, out);
  k_finalize_loss<<<1, 1, 0, stream>>>(lossp, out + (size_t)N_ * D_ + (size_t)L_ * N_);
}

// Round 5
// 2072.993 us; speedup vs baseline: 1.9601x; 1.9601x over previous
//
#include <hip/hip_runtime.h>
#include <cstdint>
#include <cstddef>

#define B_ 16
#define D_ 128
#define T_ 4500
#define N_ (B_*T_)      // 72000
#define K_ 1024
#define L_ 8
#define NRB 2250        // 32-row blocks
#define NRB_PAD 2252
#define DELTA 1.0e-4f

typedef __bf16 bf16x8 __attribute__((ext_vector_type(8)));
typedef float f32x16 __attribute__((ext_vector_type(16)));

#define GLOBAL_AS __attribute__((address_space(1)))
#define LDS_AS    __attribute__((address_space(3)))

// ---------------- helpers ----------------
// RNE f32 -> bf16 (values are tame: no NaN/Inf handling needed)
__device__ __forceinline__ unsigned short f2bf(float x) {
  unsigned u = __float_as_uint(x);
  return (unsigned short)((u + 0x7FFFu + ((u >> 16) & 1u)) >> 16);
}
// split 8 f32 into bf16 hi / bf16 lo packed as uint4 each
__device__ __forceinline__ void pack_split(const float* rn, uint4& H, uint4& L) {
  unsigned hw[8], lw[8];
#pragma unroll
  for (int i = 0; i < 8; ++i) {
    unsigned short h = f2bf(rn[i]);
    float hf = __uint_as_float(((unsigned)h) << 16);
    unsigned short lo = f2bf(__fsub_rn(rn[i], hf));
    hw[i] = h; lw[i] = lo;
  }
  H.x = hw[0] | (hw[1] << 16); H.y = hw[2] | (hw[3] << 16);
  H.z = hw[4] | (hw[5] << 16); H.w = hw[6] | (hw[7] << 16);
  L.x = lw[0] | (lw[1] << 16); L.y = lw[2] | (lw[3] << 16);
  L.z = lw[4] | (lw[5] << 16); L.w = lw[6] | (lw[7] << 16);
}

// numpy pairwise_sum (n=128) of fl(x*x): 8 stride-8 sequential chains + tree
__device__ __forceinline__ float pairwise_sq_sum128(const float* __restrict__ x) {
  float r[8];
#pragma unroll
  for (int c = 0; c < 8; ++c) r[c] = __fmul_rn(x[c], x[c]);
#pragma unroll
  for (int i = 1; i < 16; ++i)
#pragma unroll
    for (int c = 0; c < 8; ++c)
      r[c] = __fadd_rn(r[c], __fmul_rn(x[8*i + c], x[8*i + c]));
  return __fadd_rn(__fadd_rn(__fadd_rn(r[0], r[1]), __fadd_rn(r[2], r[3])),
                   __fadd_rn(__fadd_rn(r[4], r[5]), __fadd_rn(r[6], r[7])));
}

__device__ __forceinline__ float tree8(const float* rc) {
  return __fadd_rn(__fadd_rn(__fadd_rn(rc[0], rc[1]), __fadd_rn(rc[2], rc[3])),
                   __fadd_rn(__fadd_rn(rc[4], rc[5]), __fadd_rn(rc[6], rc[7])));
}

// ---------------- transpose z [B][D][T] -> R [N][D] ----------------
__global__ __launch_bounds__(256)
void k_transpose_z(const float* __restrict__ z, float* __restrict__ R) {
  __shared__ float tile[32][33];
  const int t0 = blockIdx.x * 32;
  const int d0 = blockIdx.y * 32;
  const int b  = blockIdx.z;
  const int tid = threadIdx.x;
  {
    const int jj = tid & 31; const int ii0 = (tid >> 5) * 4;
#pragma unroll
    for (int r = 0; r < 4; ++r) {
      const int ii = ii0 + r;
      float v = 0.f;
      if (t0 + jj < T_) v = z[((size_t)(b*D_ + d0 + ii))*T_ + t0 + jj];
      tile[ii][jj] = v;
    }
  }
  __syncthreads();
  {
    const int ii = tid & 31; const int jj0 = (tid >> 5) * 4;
#pragma unroll
    for (int r = 0; r < 4; ++r) {
      const int jj = jj0 + r;
      if (t0 + jj < T_)
        R[((size_t)(b*T_ + t0 + jj))*D_ + d0 + ii] = tile[ii][jj];
    }
  }
}

// ---------------- per-code squared norms (numpy pairwise) ----------------
__global__ __launch_bounds__(256)
void k_y2(const float* __restrict__ cb, float* __restrict__ y2f) {
  const int row = blockIdx.x * 256 + threadIdx.x;
  if (row >= L_ * K_) return;
  y2f[row] = pairwise_sq_sum128(&cb[(size_t)row * D_]);
}

// ---------------- codebook -> fragment-ready bf16 hi/lo ----------------
// Bpk[l][colblk(32)][s(8)][p(2)][lane(64)] : uint4 (8 bf16)
// lane: col = colblk*32 + (lane&31), k = 16s + 8*(lane>>5) + 0..7
__global__ __launch_bounds__(256)
void k_prep_b(const float* __restrict__ cb, uint4* __restrict__ Bpk) {
  const int tid = threadIdx.x;
  const int gw = blockIdx.x*4 + (tid >> 6);   // 0..255
  const int l = gw >> 5, cbk = gw & 31;
  const int lane = tid & 63, l31 = lane & 31, lh = lane >> 5;
  const int col = cbk*32 + l31;
  const float* src = cb + ((size_t)l*K_ + col)*D_ + lh*8;
  uint4* dst = Bpk + (size_t)l*32768 + (size_t)cbk*1024;
#pragma unroll
  for (int s = 0; s < 8; ++s) {
    float4 va = *(const float4*)(src + s*16);
    float4 vb = *(const float4*)(src + s*16 + 4);
    float rn[8] = {va.x, va.y, va.z, va.w, vb.x, vb.y, vb.z, vb.w};
    uint4 H, L; pack_split(rn, H, L);
    dst[(2*s+0)*64 + lane] = H;
    dst[(2*s+1)*64 + lane] = L;
  }
}

// ---------------- layer-0 split: R -> Apk(hi/lo) + x2 ----------------
__global__ __launch_bounds__(256)
void k_split0(const float* __restrict__ R, uint4* __restrict__ Apk,
              float* __restrict__ x2) {
  const int tid = threadIdx.x;
  const int rowblk = blockIdx.x*4 + (tid >> 6);
  if (rowblk >= NRB) return;
  const int lane = tid & 63, l31 = lane & 31, lh = lane >> 5;
  const int row = rowblk*32 + l31;
  const float* rr = R + (size_t)row*D_ + lh*8;
  uint4* dst = Apk + (size_t)rowblk*1024;
  float rc[8] = {0,0,0,0,0,0,0,0};
#pragma unroll
  for (int s = 0; s < 8; ++s) {
    float4 va = *(const float4*)(rr + s*16);
    float4 vb = *(const float4*)(rr + s*16 + 4);
    float rn[8] = {va.x, va.y, va.z, va.w, vb.x, vb.y, vb.z, vb.w};
    uint4 H, L; pack_split(rn, H, L);
    dst[(2*s+0)*64 + lane] = H;
    dst[(2*s+1)*64 + lane] = L;
    // numpy pairwise: lane lh=0 owns i=2s (k=16s+c), partner (lh=1) i=2s+1
#pragma unroll
    for (int c = 0; c < 8; ++c) {
      const float sq = __fmul_rn(rn[c], rn[c]);
      const float pv = __shfl_xor(sq, 32);
      rc[c] = __fadd_rn(rc[c], sq);
      rc[c] = __fadd_rn(rc[c], pv);
    }
  }
  if (lh == 0) x2[row] = tree8(rc);
}

// ---------------- MFMA screening: top-3 in u-space, candidate lists ----------------
// u_j = fl(y2_j - 2*dot_j)  (x2 is row-constant: argmin unchanged; ref-grid
// effects bounded by |ref_dv - (x2+u)| <= 2.6e-5, DELTA=1e-4 covers 2x both sides)
__global__ __launch_bounds__(256, 2)
void k_screen(const uint4* __restrict__ Apk, const uint4* __restrict__ Bpk_l,
              const float* __restrict__ y2l,
              int* __restrict__ codes, int2* __restrict__ listA,
              int* __restrict__ listB, int* __restrict__ cntA, int* __restrict__ cntB)
{
  __shared__ uint4 Bs[2][2048];   // 2 x 32KB
  const int tid = threadIdx.x;
  const int wid = tid >> 6;
  const int lane = tid & 63;
  const int l31 = lane & 31;
  const int lh  = lane >> 5;
  const int rowblk = blockIdx.x*4 + wid;
  const bool rowok = (rowblk < NRB);

  uint4 ah[8], al[8];
  {
    const uint4* ab = Apk + (size_t)rowblk*1024 + lane;
#pragma unroll
    for (int s = 0; s < 8; ++s) {
      ah[s] = ab[s*128];
      al[s] = ab[s*128 + 64];
    }
  }

  float v1[16], v2[16], v3[16]; int j1[16], j2[16];
#pragma unroll
  for (int r = 0; r < 16; ++r) {
    v1[r] = 3.0e38f; v2[r] = 3.0e38f; v3[r] = 3.0e38f; j1[r] = 0; j2[r] = 0;
  }

  // stage chunk 0
  {
    const uint4* src = Bpk_l + tid;
    LDS_AS uint4* dst = (LDS_AS uint4*)&Bs[0][tid];
#pragma unroll
    for (int i = 0; i < 8; ++i)
      __builtin_amdgcn_global_load_lds((const GLOBAL_AS void*)(src + i*256),
                                       (LDS_AS void*)(dst + i*256), 16, 0, 0);
  }

  int buf = 0;
  for (int ch = 0; ch < 16; ++ch) {
    __syncthreads();   // compiler drains vmcnt+lgkmcnt before barrier
    if (ch < 15) {
      const uint4* src = Bpk_l + (size_t)(ch+1)*2048 + tid;
      LDS_AS uint4* dst = (LDS_AS uint4*)&Bs[buf^1][tid];
#pragma unroll
      for (int i = 0; i < 8; ++i)
        __builtin_amdgcn_global_load_lds((const GLOBAL_AS void*)(src + i*256),
                                         (LDS_AS void*)(dst + i*256), 16, 0, 0);
    }
    f32x16 acc0, acc1;
#pragma unroll
    for (int r = 0; r < 16; ++r) { acc0[r] = 0.f; acc1[r] = 0.f; }
    const uint4* bb = &Bs[buf][0];
#pragma unroll
    for (int s = 0; s < 8; ++s) {
      bf16x8 Ah = __builtin_bit_cast(bf16x8, ah[s]);
      bf16x8 Al = __builtin_bit_cast(bf16x8, al[s]);
      bf16x8 bh0 = __builtin_bit_cast(bf16x8, bb[(2*s+0)*64 + lane]);
      bf16x8 bl0 = __builtin_bit_cast(bf16x8, bb[(2*s+1)*64 + lane]);
      bf16x8 bh1 = __builtin_bit_cast(bf16x8, bb[(16+2*s)*64 + lane]);
      bf16x8 bl1 = __builtin_bit_cast(bf16x8, bb[(17+2*s)*64 + lane]);
      acc0 = __builtin_amdgcn_mfma_f32_32x32x16_bf16(Ah, bh0, acc0, 0, 0, 0);
      acc1 = __builtin_amdgcn_mfma_f32_32x32x16_bf16(Ah, bh1, acc1, 0, 0, 0);
      acc0 = __builtin_amdgcn_mfma_f32_32x32x16_bf16(Al, bh0, acc0, 0, 0, 0);
      acc1 = __builtin_amdgcn_mfma_f32_32x32x16_bf16(Al, bh1, acc1, 0, 0, 0);
      acc0 = __builtin_amdgcn_mfma_f32_32x32x16_bf16(Ah, bl0, acc0, 0, 0, 0);
      acc1 = __builtin_amdgcn_mfma_f32_32x32x16_bf16(Ah, bl1, acc1, 0, 0, 0);
    }
    const int c0 = ch * 64;
    const float y2a = y2l[c0 + l31];
    const float y2b = y2l[c0 + 32 + l31];
    const int ca = c0 + l31, cbx = c0 + 32 + l31;
#pragma unroll
    for (int r = 0; r < 16; ++r) {
      const float dv0 = fmaf(-2.f, acc0[r], y2a);
      const float dv1 = fmaf(-2.f, acc1[r], y2b);
      const bool o = (dv0 <= dv1);
      const float na = o ? dv0 : dv1, xb = o ? dv1 : dv0;
      const int jna = o ? ca : cbx,  jxb = o ? cbx : ca;
      // merge sorted pair (na<=xb) into sorted top-3 (v1<=v2<=v3), idx for top-2
      const float nv3 = fminf(fminf(fmaxf(v1[r], xb), fmaxf(v2[r], na)), v3[r]);
      const float nv2 = fminf(fminf(fmaxf(v1[r], na), v2[r]), xb);
      const bool a  = na < v1[r];
      const bool bb2 = xb < v1[r];
      const bool cn = na < v2[r];
      const int oj1 = j1[r], oj2 = j2[r];
      j1[r] = a ? jna : oj1;
      j2[r] = a ? (bb2 ? jxb : oj1) : (cn ? jna : oj2);
      v1[r] = fminf(v1[r], na);
      v2[r] = nv2; v3[r] = nv3;
    }
    buf ^= 1;
  }

  // cross-lane top-3 merge within each 32-lane half (rows differ across halves)
#pragma unroll
  for (int r = 0; r < 16; ++r) {
    float a1 = v1[r], a2 = v2[r], a3 = v3[r]; int ja = j1[r], jb2 = j2[r];
#pragma unroll
    for (int off = 1; off < 32; off <<= 1) {
      const float w1 = __shfl_xor(a1, off);
      const float w2 = __shfl_xor(a2, off);
      const float w3 = __shfl_xor(a3, off);
      const int   i1 = __shfl_xor(ja, off);
      const int   i2 = __shfl_xor(jb2, off);
      // insert (w1,i1)
      float t3 = fminf(a3, fmaxf(a2, w1));
      bool c1 = w1 < a1, c2 = w1 < a2;
      float t2 = c1 ? a1 : (c2 ? w1 : a2);
      int   u2 = c1 ? ja : (c2 ? i1 : jb2);
      float t1 = c1 ? w1 : a1;
      int   u1 = c1 ? i1 : ja;
      a1 = t1; a2 = t2; a3 = t3; ja = u1; jb2 = u2;
      // insert (w2,i2)
      t3 = fminf(a3, fmaxf(a2, w2));
      c1 = w2 < a1; c2 = w2 < a2;
      t2 = c1 ? a1 : (c2 ? w2 : a2);
      u2 = c1 ? ja : (c2 ? i2 : jb2);
      t1 = c1 ? w2 : a1;
      u1 = c1 ? i2 : ja;
      a1 = t1; a2 = t2; a3 = t3; ja = u1; jb2 = u2;
      a3 = fminf(a3, w3);
    }
    if (l31 == 0 && rowok) {
      const int n = rowblk*32 + (r&3) + 8*(r>>2) + 4*lh;
      codes[n] = ja;
      if (a3 - a1 <= DELTA) {                       // >=3 candidates: full scan
        const int p = atomicAdd(cntB, 1);
        listB[p] = n;
      } else if (a2 - a1 <= DELTA) {                // exactly 2 candidates
        const int p = atomicAdd(cntA, 1);
        listA[p] = make_int2(n, jb2);
      }
    }
  }
}

// ---------------- mode A: exact pair rescore (one lane per row) ----------------
__global__ __launch_bounds__(256)
void k_fixupA(const float* __restrict__ R, const float* __restrict__ cbl,
              const float* __restrict__ x2, const float* __restrict__ y2l,
              const int* __restrict__ cntA, const int2* __restrict__ listA,
              int* __restrict__ codes)
{
  const int C = cntA[0];
  for (int idx = blockIdx.x*256 + threadIdx.x; idx < C; idx += gridDim.x*256) {
    const int2 e = listA[idx];
    const int n = e.x;
    const int ja = codes[n], jb = e.y;
    const float* xr = &R[(size_t)n*D_];
    const float* pa = &cbl[(size_t)ja*D_];
    const float* pb = &cbl[(size_t)jb*D_];
    float s1 = 0.f, s2 = 0.f;
#pragma unroll
    for (int k = 0; k < D_; k += 4) {   // strict ascending-k BLAS chain
      const float4 x = *(const float4*)(xr + k);
      const float4 A = *(const float4*)(pa + k);
      const float4 Bv = *(const float4*)(pb + k);
      s1 = fmaf(x.x, A.x, s1);  s1 = fmaf(x.y, A.y, s1);
      s1 = fmaf(x.z, A.z, s1);  s1 = fmaf(x.w, A.w, s1);
      s2 = fmaf(x.x, Bv.x, s2); s2 = fmaf(x.y, Bv.y, s2);
      s2 = fmaf(x.z, Bv.z, s2); s2 = fmaf(x.w, Bv.w, s2);
    }
    const float x2n = x2[n];
    const float d1 = __fsub_rn(__fadd_rn(x2n, y2l[ja]), __fmul_rn(2.f, s1));
    const float d2 = __fsub_rn(__fadd_rn(x2n, y2l[jb]), __fmul_rn(2.f, s2));
    const bool take2 = (d2 < d1) || (d2 == d1 && jb < ja);
    if (take2) codes[n] = jb;
  }
}

// ---------------- mode B: exact full-scan fixup (rare rows) ----------------
__global__ __launch_bounds__(256)
void k_fixupB(const float* __restrict__ R, const float* __restrict__ cbl,
              const float* __restrict__ x2, const float* __restrict__ y2l,
              const int* __restrict__ cntB, const int* __restrict__ listB,
              int* __restrict__ codes)
{
  __shared__ float rs[4][128];
  const int tid = threadIdx.x;
  const int wid = tid >> 6, lane = tid & 63;
  const int nw = gridDim.x * 4;
  const int gw = blockIdx.x*4 + wid;
  const int C = *cntB;
  for (int it = gw; it < C; it += nw) {
    const int n = listB[it];
    float2 t = *(const float2*)&R[(size_t)n*D_ + lane*2];
    rs[wid][lane*2] = t.x; rs[wid][lane*2+1] = t.y;
    asm volatile("s_waitcnt lgkmcnt(0)" ::: "memory");
    const float x2n = x2[n];
    float acc[16];
#pragma unroll
    for (int q = 0; q < 16; ++q) acc[q] = 0.f;
    for (int k = 0; k < 128; k += 4) {
      float4 rv = *(const float4*)&rs[wid][k];
#pragma unroll
      for (int q = 0; q < 16; ++q) {
        const float4 cv = *(const float4*)&cbl[(size_t)(q*64 + lane)*D_ + k];
        acc[q] = fmaf(rv.x, cv.x, acc[q]);
        acc[q] = fmaf(rv.y, cv.y, acc[q]);
        acc[q] = fmaf(rv.z, cv.z, acc[q]);
        acc[q] = fmaf(rv.w, cv.w, acc[q]);
      }
    }
    float vb = 3.0e38f; int jb = 0;
#pragma unroll
    for (int q = 0; q < 16; ++q) {
      const int j = q*64 + lane;
      float dv = fmaf(-2.f, acc[q], __fadd_rn(x2n, y2l[j]));
      if (dv < vb) { vb = dv; jb = j; }   // j ascends with q: ties keep lower
    }
#pragma unroll
    for (int off = 1; off < 64; off <<= 1) {
      float bv = __shfl_xor(vb, off);
      int   bj = __shfl_xor(jb, off);
      if (bv < vb || (bv == vb && bj < jb)) { vb = bv; jb = bj; }
    }
    if (lane == 0) codes[n] = jb;
    asm volatile("s_waitcnt lgkmcnt(0)" ::: "memory");
  }
}

// ---------------- residual update + split + x2 + loss + codes out ----------------
__global__ __launch_bounds__(256)
void k_update(float* __restrict__ R, const float* __restrict__ cbl,
              const int* __restrict__ codes, uint4* __restrict__ Apk,
              float* __restrict__ x2, float* __restrict__ out_codes,
              float* __restrict__ lossp, int last)
{
  const int tid = threadIdx.x;
  const int rowblk = blockIdx.x*4 + (tid >> 6);
  const int lane = tid & 63, l31 = lane & 31, lh = lane >> 5;
  const bool active = (rowblk < NRB);
  float ss = 0.f;
  if (active) {
    const int row = rowblk*32 + l31;
    const int code = codes[row];
    float* rr = R + (size_t)row*D_ + lh*8;
    const float* cr = cbl + (size_t)code*D_ + lh*8;
    uint4* dst = Apk + (size_t)rowblk*1024;
    float rc[8] = {0,0,0,0,0,0,0,0};
#pragma unroll
    for (int s = 0; s < 8; ++s) {
      float4 xa = *(const float4*)(rr + s*16);
      float4 xb = *(const float4*)(rr + s*16 + 4);
      float4 qa = *(const float4*)(cr + s*16);
      float4 qb = *(const float4*)(cr + s*16 + 4);
      float rn[8];
      rn[0] = __fsub_rn(xa.x, qa.x); rn[1] = __fsub_rn(xa.y, qa.y);
      rn[2] = __fsub_rn(xa.z, qa.z); rn[3] = __fsub_rn(xa.w, qa.w);
      rn[4] = __fsub_rn(xb.x, qb.x); rn[5] = __fsub_rn(xb.y, qb.y);
      rn[6] = __fsub_rn(xb.z, qb.z); rn[7] = __fsub_rn(xb.w, qb.w);
      *(float4*)(rr + s*16)     = make_float4(rn[0], rn[1], rn[2], rn[3]);
      *(float4*)(rr + s*16 + 4) = make_float4(rn[4], rn[5], rn[6], rn[7]);
#pragma unroll
      for (int c = 0; c < 8; ++c) ss = fmaf(rn[c], rn[c], ss);
      if (!last) {
        uint4 H, L; pack_split(rn, H, L);
        dst[(2*s+0)*64 + lane] = H;
        dst[(2*s+1)*64 + lane] = L;
      }
#pragma unroll
      for (int c = 0; c < 8; ++c) {
        const float sq = __fmul_rn(rn[c], rn[c]);
        const float pv = __shfl_xor(sq, 32);
        rc[c] = __fadd_rn(rc[c], sq);
        rc[c] = __fadd_rn(rc[c], pv);
      }
    }
    if (lh == 0) {
      if (!last) x2[row] = tree8(rc);
      out_codes[row] = (float)code;
    }
  }
#pragma unroll
  for (int off = 1; off < 64; off <<= 1) ss += __shfl_xor(ss, off);
  if (active && lane == 0) atomicAdd(lossp, ss);
}

// ---------------- finalize ----------------
__global__ __launch_bounds__(256)
void k_finalize_quant(const float* __restrict__ z, const float* __restrict__ R,
                      float* __restrict__ out) {
  __shared__ float tile[32][33];
  const int t0 = blockIdx.x * 32;
  const int d0 = blockIdx.y * 32;
  const int b  = blockIdx.z;
  const int tid = threadIdx.x;
  {
    const int ii = tid & 31; const int jj0 = (tid >> 5) * 4;
#pragma unroll
    for (int r = 0; r < 4; ++r) {
      const int jj = jj0 + r;
      tile[ii][jj] = (t0 + jj < T_) ? R[((size_t)(b*T_ + t0 + jj))*D_ + d0 + ii] : 0.f;
    }
  }
  __syncthreads();
  {
    const int jj = tid & 31; const int ii0 = (tid >> 5) * 4;
#pragma unroll
    for (int r = 0; r < 4; ++r) {
      const int ii = ii0 + r;
      if (t0 + jj < T_) {
        const size_t gi = ((size_t)(b*D_ + d0 + ii))*T_ + t0 + jj;
        out[gi] = __fsub_rn(z[gi], tile[ii][jj]);
      }
    }
  }
}

__global__ void k_finalize_loss(const float* __restrict__ lossp, float* __restrict__ out2) {
  const float lv = (float)((double)lossp[0] / (double)((size_t)N_ * D_));
  out2[0] = lv;
  out2[1] = lv;
}

// ---------------- host launch ----------------
extern "C" void kernel_launch(void* const* d_in, const int* in_sizes, int n_in,
                              void* d_out, int out_size, void* d_ws, size_t ws_size,
                              hipStream_t stream) {
  const float* z  = (const float*)d_in[0];
  const float* cb = (const float*)d_in[1];
  float* out = (float*)d_out;

  char* ws = (char*)d_ws;
  const size_t OFF_R     = 0;
  const size_t OFF_APK   = OFF_R + (size_t)N_ * D_ * 4;         // 36,864,000
  const size_t OFF_BPK   = OFF_APK + (size_t)NRB_PAD * 16384;   // 73,760,768
  const size_t OFF_Y2    = OFF_BPK + (size_t)L_ * 32768 * 16;   // 77,955,072
  const size_t OFF_X2    = OFF_Y2 + (size_t)L_ * K_ * 4;        // 77,987,840
  const size_t OFF_CODES = OFF_X2 + (size_t)NRB_PAD * 32 * 4;   // 78,276,096
  const size_t OFF_LISTA = OFF_CODES + (size_t)N_ * 4;          // 78,564,096
  const size_t OFF_LISTB = OFF_LISTA + (size_t)N_ * 8;          // 79,140,096
  const size_t OFF_CTR   = OFF_LISTB + (size_t)N_ * 4;          // 79,428,096

  float* R     = (float*)(ws + OFF_R);
  uint4* Apk   = (uint4*)(ws + OFF_APK);
  uint4* Bpk   = (uint4*)(ws + OFF_BPK);
  float* y2f   = (float*)(ws + OFF_Y2);
  float* x2    = (float*)(ws + OFF_X2);
  int*   codes = (int*)(ws + OFF_CODES);
  int2*  listA = (int2*)(ws + OFF_LISTA);
  int*   listB = (int*)(ws + OFF_LISTB);
  int*   ctrs  = (int*)(ws + OFF_CTR);      // [2*l]=cntA, [2*l+1]=cntB
  float* lossp = (float*)(ws + OFF_CTR + 64);

  hipMemsetAsync(ws + OFF_CTR, 0, 72, stream);

  k_transpose_z<<<dim3((T_ + 31)/32, D_/32, B_), 256, 0, stream>>>(z, R);
  k_y2<<<(L_ * K_)/256, 256, 0, stream>>>(cb, y2f);
  k_prep_b<<<64, 256, 0, stream>>>(cb, Bpk);
  k_split0<<<563, 256, 0, stream>>>(R, Apk, x2);

  for (int l = 0; l < L_; ++l) {
    k_screen<<<563, 256, 0, stream>>>(
        Apk, Bpk + (size_t)l * 32768, y2f + (size_t)l * K_,
        codes, listA, listB, ctrs + 2*l, ctrs + 2*l + 1);
    k_fixupA<<<282, 256, 0, stream>>>(
        R, cb + (size_t)l * K_ * D_, x2, y2f + (size_t)l * K_,
        ctrs + 2*l, listA, codes);
    k_fixupB<<<563, 256, 0, stream>>>(
        R, cb + (size_t)l * K_ * D_, x2, y2f + (size_t)l * K_,
        ctrs + 2*l + 1, listB, codes);
    k_update<<<563, 256, 0, stream>>>(
        R, cb + (size_t)l * K_ * D_, codes, Apk, x2,
        out + (size_t)N_ * D_ + (size_t)l * N_, lossp, (l == L_ - 1) ? 1 : 0);
  }

  k_finalize_quant<<<dim3((T_ + 31)/32, D_/32, B_), 256, 0, stream>>>(z, R, out);
  k_finalize_loss<<<1, 1, 0, stream>>>(lossp, out + (size_t)N_ * D_ + (size_t)L_ * N_);
}

// Round 6
// 1900.135 us; speedup vs baseline: 2.1384x; 1.0910x over previous
//
#include <hip/hip_runtime.h>
#include <cstdint>
#include <cstddef>

#define B_ 16
#define D_ 128
#define T_ 4500
#define N_ (B_*T_)      // 72000
#define K_ 1024
#define L_ 8
#define NRB 2250        // 32-row blocks (exactly 72000/32)
#define DELTA 7.0e-5f

typedef __bf16 bf16x8 __attribute__((ext_vector_type(8)));
typedef float f32x16 __attribute__((ext_vector_type(16)));

// ---------------- helpers ----------------
// RNE f32 -> bf16 (values are tame: no NaN/Inf handling needed)
__device__ __forceinline__ unsigned short f2bf(float x) {
  unsigned u = __float_as_uint(x);
  return (unsigned short)((u + 0x7FFFu + ((u >> 16) & 1u)) >> 16);
}
// split 8 f32 into bf16 hi / bf16 lo packed as uint4 each
__device__ __forceinline__ void pack_split(const float* rn, uint4& H, uint4& L) {
  unsigned hw[8], lw[8];
#pragma unroll
  for (int i = 0; i < 8; ++i) {
    unsigned short h = f2bf(rn[i]);
    float hf = __uint_as_float(((unsigned)h) << 16);
    unsigned short lo = f2bf(__fsub_rn(rn[i], hf));
    hw[i] = h; lw[i] = lo;
  }
  H.x = hw[0] | (hw[1] << 16); H.y = hw[2] | (hw[3] << 16);
  H.z = hw[4] | (hw[5] << 16); H.w = hw[6] | (hw[7] << 16);
  L.x = lw[0] | (lw[1] << 16); L.y = lw[2] | (lw[3] << 16);
  L.z = lw[4] | (lw[5] << 16); L.w = lw[6] | (lw[7] << 16);
}

// numpy pairwise_sum (n=128) of fl(x*x): 8 stride-8 sequential chains + tree
__device__ __forceinline__ float pairwise_sq_sum128(const float* __restrict__ x) {
  float r[8];
#pragma unroll
  for (int c = 0; c < 8; ++c) r[c] = __fmul_rn(x[c], x[c]);
#pragma unroll
  for (int i = 1; i < 16; ++i)
#pragma unroll
    for (int c = 0; c < 8; ++c)
      r[c] = __fadd_rn(r[c], __fmul_rn(x[8*i + c], x[8*i + c]));
  return __fadd_rn(__fadd_rn(__fadd_rn(r[0], r[1]), __fadd_rn(r[2], r[3])),
                   __fadd_rn(__fadd_rn(r[4], r[5]), __fadd_rn(r[6], r[7])));
}

__device__ __forceinline__ float tree8(const float* rc) {
  return __fadd_rn(__fadd_rn(__fadd_rn(rc[0], rc[1]), __fadd_rn(rc[2], rc[3])),
                   __fadd_rn(__fadd_rn(rc[4], rc[5]), __fadd_rn(rc[6], rc[7])));
}

// ---------------- transpose z [B][D][T] -> R [N][D] ----------------
__global__ __launch_bounds__(256)
void k_transpose_z(const float* __restrict__ z, float* __restrict__ R) {
  __shared__ float tile[32][33];
  const int t0 = blockIdx.x * 32;
  const int d0 = blockIdx.y * 32;
  const int b  = blockIdx.z;
  const int tid = threadIdx.x;
  {
    const int jj = tid & 31; const int ii0 = (tid >> 5) * 4;
#pragma unroll
    for (int r = 0; r < 4; ++r) {
      const int ii = ii0 + r;
      float v = 0.f;
      if (t0 + jj < T_) v = z[((size_t)(b*D_ + d0 + ii))*T_ + t0 + jj];
      tile[ii][jj] = v;
    }
  }
  __syncthreads();
  {
    const int ii = tid & 31; const int jj0 = (tid >> 5) * 4;
#pragma unroll
    for (int r = 0; r < 4; ++r) {
      const int jj = jj0 + r;
      if (t0 + jj < T_)
        R[((size_t)(b*T_ + t0 + jj))*D_ + d0 + ii] = tile[ii][jj];
    }
  }
}

// ---------------- transpose cb [L][K][D] -> cbT [L][D][K] ----------------
__global__ __launch_bounds__(256)
void k_transpose_cb(const float* __restrict__ cb, float* __restrict__ cbT) {
  __shared__ float tile[32][33];
  const int j0 = blockIdx.x * 32;
  const int d0 = blockIdx.y * 32;
  const int l  = blockIdx.z;
  const int tid = threadIdx.x;
  {
    const int dd = tid & 31; const int jj0 = (tid >> 5) * 4;
#pragma unroll
    for (int r = 0; r < 4; ++r)
      tile[jj0 + r][dd] = cb[((size_t)(l*K_ + j0 + jj0 + r))*D_ + d0 + dd];
  }
  __syncthreads();
  {
    const int jj = tid & 31; const int dd0 = (tid >> 5) * 4;
#pragma unroll
    for (int r = 0; r < 4; ++r)
      cbT[((size_t)(l*D_ + d0 + dd0 + r))*K_ + j0 + jj] = tile[jj][dd0 + r];
  }
}

// ---------------- per-code squared norms (numpy pairwise) ----------------
__global__ __launch_bounds__(256)
void k_y2(const float* __restrict__ cb, float* __restrict__ y2f) {
  const int row = blockIdx.x * 256 + threadIdx.x;
  if (row >= L_ * K_) return;
  y2f[row] = pairwise_sq_sum128(&cb[(size_t)row * D_]);
}

// ---------------- codebook -> fragment-ready bf16 hi/lo ----------------
// Bpk[l][colblk(32)][s(8)][p(2)][lane(64)] : uint4 (8 bf16)
// lane: col = colblk*32 + (lane&31), k = 16s + 8*(lane>>5) + 0..7
__global__ __launch_bounds__(256)
void k_prep_b(const float* __restrict__ cb, uint4* __restrict__ Bpk) {
  const int tid = threadIdx.x;
  const int gw = blockIdx.x*4 + (tid >> 6);   // 0..255
  const int l = gw >> 5, cbk = gw & 31;
  const int lane = tid & 63, l31 = lane & 31, lh = lane >> 5;
  const int col = cbk*32 + l31;
  const float* src = cb + ((size_t)l*K_ + col)*D_ + lh*8;
  uint4* dst = Bpk + (size_t)l*32768 + (size_t)cbk*1024;
#pragma unroll
  for (int s = 0; s < 8; ++s) {
    float4 va = *(const float4*)(src + s*16);
    float4 vb = *(const float4*)(src + s*16 + 4);
    float rn[8] = {va.x, va.y, va.z, va.w, vb.x, vb.y, vb.z, vb.w};
    uint4 H, L; pack_split(rn, H, L);
    dst[(2*s+0)*64 + lane] = H;
    dst[(2*s+1)*64 + lane] = L;
  }
}

// ---------------- x2 init (layer 0): numpy-pairwise sum of squares ----------------
__global__ __launch_bounds__(256)
void k_x2g(const float* __restrict__ R, float* __restrict__ x2) {
  const int tid = threadIdx.x;
  const int rowblk = blockIdx.x*4 + (tid >> 6);
  if (rowblk >= NRB) return;
  const int lane = tid & 63, l31 = lane & 31, lh = lane >> 5;
  const int row = rowblk*32 + l31;
  const float* rr = R + (size_t)row*D_ + lh*8;
  float rc[8] = {0,0,0,0,0,0,0,0};
#pragma unroll
  for (int s = 0; s < 8; ++s) {
    const float4 va = *(const float4*)(rr + s*16);
    const float4 vb = *(const float4*)(rr + s*16 + 4);
    const float rn[8] = {va.x, va.y, va.z, va.w, vb.x, vb.y, vb.z, vb.w};
#pragma unroll
    for (int c = 0; c < 8; ++c) {
      const float sq = __fmul_rn(rn[c], rn[c]);
      const float pv = __shfl_xor(sq, 32);
      rc[c] = __fadd_rn(rc[c], sq);
      rc[c] = __fadd_rn(rc[c], pv);
    }
  }
  if (lh == 0) x2[row] = tree8(rc);
}

// ---------------- MFMA screening: barrier-free, B direct from global ----------------
// u_j = fl(y2_j - 2*dot_j); top-3 values + top-2 indices per row; candidate lists.
__global__ __launch_bounds__(256, 2)
void k_screen(const float* __restrict__ R, const uint4* __restrict__ Bpk_l,
              const float* __restrict__ y2l,
              int* __restrict__ codes, int2* __restrict__ listA,
              int* __restrict__ listB, int* __restrict__ cntA, int* __restrict__ cntB)
{
  const int tid = threadIdx.x;
  const int rowblk = blockIdx.x*4 + (tid >> 6);
  if (rowblk >= NRB) return;
  const int lane = tid & 63, l31 = lane & 31, lh = lane >> 5;

  // load + split A fragments in-reg (same k-map as k_prep_b: k = 16s + 8*lh + c)
  uint4 ah[8], al[8];
  {
    const float* rr = R + ((size_t)rowblk*32 + l31)*D_ + lh*8;
#pragma unroll
    for (int s = 0; s < 8; ++s) {
      const float4 va = *(const float4*)(rr + s*16);
      const float4 vb = *(const float4*)(rr + s*16 + 4);
      const float rn[8] = {va.x, va.y, va.z, va.w, vb.x, vb.y, vb.z, vb.w};
      pack_split(rn, ah[s], al[s]);
    }
  }

  float v1[16], v2[16], v3[16]; int j1[16], j2[16];
#pragma unroll
  for (int r = 0; r < 16; ++r) {
    v1[r] = 3.0e38f; v2[r] = 3.0e38f; v3[r] = 3.0e38f; j1[r] = 0; j2[r] = 0;
  }

  for (int ch = 0; ch < 16; ++ch) {
    const uint4* bb = Bpk_l + (size_t)ch*2048 + lane;
    f32x16 acc0, acc1;
#pragma unroll
    for (int r = 0; r < 16; ++r) { acc0[r] = 0.f; acc1[r] = 0.f; }
#pragma unroll
    for (int s = 0; s < 8; ++s) {
      const bf16x8 Ah = __builtin_bit_cast(bf16x8, ah[s]);
      const bf16x8 Al = __builtin_bit_cast(bf16x8, al[s]);
      const bf16x8 bh0 = __builtin_bit_cast(bf16x8, bb[(2*s+0)*64]);
      const bf16x8 bl0 = __builtin_bit_cast(bf16x8, bb[(2*s+1)*64]);
      const bf16x8 bh1 = __builtin_bit_cast(bf16x8, bb[1024 + (2*s+0)*64]);
      const bf16x8 bl1 = __builtin_bit_cast(bf16x8, bb[1024 + (2*s+1)*64]);
      acc0 = __builtin_amdgcn_mfma_f32_32x32x16_bf16(Ah, bh0, acc0, 0, 0, 0);
      acc1 = __builtin_amdgcn_mfma_f32_32x32x16_bf16(Ah, bh1, acc1, 0, 0, 0);
      acc0 = __builtin_amdgcn_mfma_f32_32x32x16_bf16(Al, bh0, acc0, 0, 0, 0);
      acc1 = __builtin_amdgcn_mfma_f32_32x32x16_bf16(Al, bh1, acc1, 0, 0, 0);
      acc0 = __builtin_amdgcn_mfma_f32_32x32x16_bf16(Ah, bl0, acc0, 0, 0, 0);
      acc1 = __builtin_amdgcn_mfma_f32_32x32x16_bf16(Ah, bl1, acc1, 0, 0, 0);
    }
    const int c0 = ch * 64;
    const float y2a = y2l[c0 + l31];
    const float y2b = y2l[c0 + 32 + l31];
    const int ca = c0 + l31, cbx = c0 + 32 + l31;
#pragma unroll
    for (int r = 0; r < 16; ++r) {
      const float dv0 = fmaf(-2.f, acc0[r], y2a);
      const float dv1 = fmaf(-2.f, acc1[r], y2b);
      const bool o = (dv0 <= dv1);
      const float na = o ? dv0 : dv1, xb = o ? dv1 : dv0;
      const int jna = o ? ca : cbx,  jxb = o ? cbx : ca;
      // merge sorted pair (na<=xb) into sorted top-3 (v1<=v2<=v3), idx for top-2
      const float nv3 = fminf(fminf(fmaxf(v1[r], xb), fmaxf(v2[r], na)), v3[r]);
      const float nv2 = fminf(fminf(fmaxf(v1[r], na), v2[r]), xb);
      const bool a  = na < v1[r];
      const bool bb2 = xb < v1[r];
      const bool cn = na < v2[r];
      const int oj1 = j1[r], oj2 = j2[r];
      j1[r] = a ? jna : oj1;
      j2[r] = a ? (bb2 ? jxb : oj1) : (cn ? jna : oj2);
      v1[r] = fminf(v1[r], na);
      v2[r] = nv2; v3[r] = nv3;
    }
  }

  // cross-lane top-3 merge within each 32-lane half (rows differ across halves)
#pragma unroll
  for (int r = 0; r < 16; ++r) {
    float a1 = v1[r], a2 = v2[r], a3 = v3[r]; int ja = j1[r], jb2 = j2[r];
#pragma unroll
    for (int off = 1; off < 32; off <<= 1) {
      const float w1 = __shfl_xor(a1, off);
      const float w2 = __shfl_xor(a2, off);
      const float w3 = __shfl_xor(a3, off);
      const int   i1 = __shfl_xor(ja, off);
      const int   i2 = __shfl_xor(jb2, off);
      // insert (w1,i1)
      float t3 = fminf(a3, fmaxf(a2, w1));
      bool c1 = w1 < a1, c2 = w1 < a2;
      float t2 = c1 ? a1 : (c2 ? w1 : a2);
      int   u2 = c1 ? ja : (c2 ? i1 : jb2);
      float t1 = c1 ? w1 : a1;
      int   u1 = c1 ? i1 : ja;
      a1 = t1; a2 = t2; a3 = t3; ja = u1; jb2 = u2;
      // insert (w2,i2)
      t3 = fminf(a3, fmaxf(a2, w2));
      c1 = w2 < a1; c2 = w2 < a2;
      t2 = c1 ? a1 : (c2 ? w2 : a2);
      u2 = c1 ? ja : (c2 ? i2 : jb2);
      t1 = c1 ? w2 : a1;
      u1 = c1 ? i2 : ja;
      a1 = t1; a2 = t2; a3 = t3; ja = u1; jb2 = u2;
      a3 = fminf(a3, w3);
    }
    if (l31 == 0) {
      const int n = rowblk*32 + (r&3) + 8*(r>>2) + 4*lh;
      codes[n] = ja;
      if (a3 - a1 <= DELTA) {                       // >=3 candidates: full scan
        const int p = atomicAdd(cntB, 1);
        listB[p] = n;
      } else if (a2 - a1 <= DELTA) {                // exactly 2 candidates
        const int p = atomicAdd(cntA, 1);
        listA[p] = make_int2(n, jb2);
      }
    }
  }
}

// ---------------- mode A: exact pair rescore (one lane per row) ----------------
__global__ __launch_bounds__(256)
void k_fixupA(const float* __restrict__ R, const float* __restrict__ cbl,
              const float* __restrict__ x2, const float* __restrict__ y2l,
              const int* __restrict__ cntA, const int2* __restrict__ listA,
              int* __restrict__ codes)
{
  const int C = cntA[0];
  for (int idx = blockIdx.x*256 + threadIdx.x; idx < C; idx += gridDim.x*256) {
    const int2 e = listA[idx];
    const int n = e.x;
    const int ja = codes[n], jb = e.y;
    const float* xr = &R[(size_t)n*D_];
    const float* pa = &cbl[(size_t)ja*D_];
    const float* pb = &cbl[(size_t)jb*D_];
    float s1 = 0.f, s2 = 0.f;
#pragma unroll
    for (int k = 0; k < D_; k += 4) {   // strict ascending-k BLAS chain
      const float4 x = *(const float4*)(xr + k);
      const float4 A = *(const float4*)(pa + k);
      const float4 Bv = *(const float4*)(pb + k);
      s1 = fmaf(x.x, A.x, s1);  s1 = fmaf(x.y, A.y, s1);
      s1 = fmaf(x.z, A.z, s1);  s1 = fmaf(x.w, A.w, s1);
      s2 = fmaf(x.x, Bv.x, s2); s2 = fmaf(x.y, Bv.y, s2);
      s2 = fmaf(x.z, Bv.z, s2); s2 = fmaf(x.w, Bv.w, s2);
    }
    const float x2n = x2[n];
    const float d1 = __fsub_rn(__fadd_rn(x2n, y2l[ja]), __fmul_rn(2.f, s1));
    const float d2 = __fsub_rn(__fadd_rn(x2n, y2l[jb]), __fmul_rn(2.f, s2));
    const bool take2 = (d2 < d1) || (d2 == d1 && jb < ja);
    if (take2) codes[n] = jb;
  }
}

// ---------------- mode B: exact full-scan fixup (coalesced via cbT) ----------------
__global__ __launch_bounds__(256)
void k_fixupB(const float* __restrict__ R, const float* __restrict__ cbTl,
              const float* __restrict__ x2, const float* __restrict__ y2l,
              const int* __restrict__ cntB, const int* __restrict__ listB,
              int* __restrict__ codes)
{
  __shared__ float rs[4][128];
  const int tid = threadIdx.x;
  const int wid = tid >> 6, lane = tid & 63;
  const int nw = gridDim.x * 4;
  const int gw = blockIdx.x*4 + wid;
  const int C = *cntB;
  for (int it = gw; it < C; it += nw) {
    const int n = listB[it];
    const float2 t = *(const float2*)&R[(size_t)n*D_ + lane*2];
    rs[wid][lane*2] = t.x; rs[wid][lane*2+1] = t.y;
    asm volatile("s_waitcnt lgkmcnt(0)" ::: "memory");
    const float x2n = x2[n];
    float acc[16];
#pragma unroll
    for (int q = 0; q < 16; ++q) acc[q] = 0.f;
    for (int k = 0; k < 128; ++k) {       // ascending k: exact BLAS chain per j
      const float rv = rs[wid][k];
      const float* cr = cbTl + (size_t)k*K_ + lane;
#pragma unroll
      for (int q = 0; q < 16; ++q)
        acc[q] = fmaf(rv, cr[q*64], acc[q]);   // coalesced 64-lane reads
    }
    float vb = 3.0e38f; int jb = 0;
#pragma unroll
    for (int q = 0; q < 16; ++q) {
      const int j = q*64 + lane;
      const float dv = fmaf(-2.f, acc[q], __fadd_rn(x2n, y2l[j]));
      if (dv < vb) { vb = dv; jb = j; }   // j ascends with q: ties keep lower
    }
#pragma unroll
    for (int off = 1; off < 64; off <<= 1) {
      const float bv = __shfl_xor(vb, off);
      const int   bj = __shfl_xor(jb, off);
      if (bv < vb || (bv == vb && bj < jb)) { vb = bv; jb = bj; }
    }
    if (lane == 0) codes[n] = jb;
    asm volatile("s_waitcnt lgkmcnt(0)" ::: "memory");  // rs reuse (per-wave)
  }
}

// ---------------- residual update + x2 + loss + codes out ----------------
__global__ __launch_bounds__(256)
void k_update(float* __restrict__ R, const float* __restrict__ cbl,
              const int* __restrict__ codes,
              float* __restrict__ x2, float* __restrict__ out_codes,
              float* __restrict__ lossp)
{
  const int tid = threadIdx.x;
  const int rowblk = blockIdx.x*4 + (tid >> 6);
  const int lane = tid & 63, l31 = lane & 31, lh = lane >> 5;
  const bool active = (rowblk < NRB);
  float ss = 0.f;
  if (active) {
    const int row = rowblk*32 + l31;
    const int code = codes[row];
    float* rr = R + (size_t)row*D_ + lh*8;
    const float* cr = cbl + (size_t)code*D_ + lh*8;
    float rc[8] = {0,0,0,0,0,0,0,0};
#pragma unroll
    for (int s = 0; s < 8; ++s) {
      const float4 xa = *(const float4*)(rr + s*16);
      const float4 xb = *(const float4*)(rr + s*16 + 4);
      const float4 qa = *(const float4*)(cr + s*16);
      const float4 qb = *(const float4*)(cr + s*16 + 4);
      float rn[8];
      rn[0] = __fsub_rn(xa.x, qa.x); rn[1] = __fsub_rn(xa.y, qa.y);
      rn[2] = __fsub_rn(xa.z, qa.z); rn[3] = __fsub_rn(xa.w, qa.w);
      rn[4] = __fsub_rn(xb.x, qb.x); rn[5] = __fsub_rn(xb.y, qb.y);
      rn[6] = __fsub_rn(xb.z, qb.z); rn[7] = __fsub_rn(xb.w, qb.w);
      *(float4*)(rr + s*16)     = make_float4(rn[0], rn[1], rn[2], rn[3]);
      *(float4*)(rr + s*16 + 4) = make_float4(rn[4], rn[5], rn[6], rn[7]);
#pragma unroll
      for (int c = 0; c < 8; ++c) ss = fmaf(rn[c], rn[c], ss);
#pragma unroll
      for (int c = 0; c < 8; ++c) {
        const float sq = __fmul_rn(rn[c], rn[c]);
        const float pv = __shfl_xor(sq, 32);
        rc[c] = __fadd_rn(rc[c], sq);
        rc[c] = __fadd_rn(rc[c], pv);
      }
    }
    if (lh == 0) {
      x2[row] = tree8(rc);
      out_codes[row] = (float)code;
    }
  }
#pragma unroll
  for (int off = 1; off < 64; off <<= 1) ss += __shfl_xor(ss, off);
  if (active && lane == 0) atomicAdd(lossp, ss);
}

// ---------------- finalize ----------------
__global__ __launch_bounds__(256)
void k_finalize_quant(const float* __restrict__ z, const float* __restrict__ R,
                      float* __restrict__ out) {
  __shared__ float tile[32][33];
  const int t0 = blockIdx.x * 32;
  const int d0 = blockIdx.y * 32;
  const int b  = blockIdx.z;
  const int tid = threadIdx.x;
  {
    const int ii = tid & 31; const int jj0 = (tid >> 5) * 4;
#pragma unroll
    for (int r = 0; r < 4; ++r) {
      const int jj = jj0 + r;
      tile[ii][jj] = (t0 + jj < T_) ? R[((size_t)(b*T_ + t0 + jj))*D_ + d0 + ii] : 0.f;
    }
  }
  __syncthreads();
  {
    const int jj = tid & 31; const int ii0 = (tid >> 5) * 4;
#pragma unroll
    for (int r = 0; r < 4; ++r) {
      const int ii = ii0 + r;
      if (t0 + jj < T_) {
        const size_t gi = ((size_t)(b*D_ + d0 + ii))*T_ + t0 + jj;
        out[gi] = __fsub_rn(z[gi], tile[ii][jj]);
      }
    }
  }
}

__global__ void k_finalize_loss(const float* __restrict__ lossp, float* __restrict__ out2) {
  const float lv = (float)((double)lossp[0] / (double)((size_t)N_ * D_));
  out2[0] = lv;
  out2[1] = lv;
}

// ---------------- host launch ----------------
extern "C" void kernel_launch(void* const* d_in, const int* in_sizes, int n_in,
                              void* d_out, int out_size, void* d_ws, size_t ws_size,
                              hipStream_t stream) {
  const float* z  = (const float*)d_in[0];
  const float* cb = (const float*)d_in[1];
  float* out = (float*)d_out;

  char* ws = (char*)d_ws;
  const size_t OFF_R     = 0;
  const size_t OFF_BPK   = OFF_R     + (size_t)N_ * D_ * 4;        // 36,864,000
  const size_t OFF_CBT   = OFF_BPK   + (size_t)L_ * 32768 * 16;    // 41,058,304
  const size_t OFF_Y2    = OFF_CBT   + (size_t)L_ * D_ * K_ * 4;   // 45,252,608
  const size_t OFF_X2    = OFF_Y2    + (size_t)L_ * K_ * 4;        // 45,285,376
  const size_t OFF_CODES = OFF_X2    + (size_t)N_ * 4;             // 45,573,376
  const size_t OFF_LISTA = OFF_CODES + (size_t)N_ * 4;             // 45,861,376
  const size_t OFF_LISTB = OFF_LISTA + (size_t)N_ * 8;             // 46,437,376
  const size_t OFF_CTR   = OFF_LISTB + (size_t)N_ * 4;             // 46,725,376

  float* R     = (float*)(ws + OFF_R);
  uint4* Bpk   = (uint4*)(ws + OFF_BPK);
  float* cbT   = (float*)(ws + OFF_CBT);
  float* y2f   = (float*)(ws + OFF_Y2);
  float* x2    = (float*)(ws + OFF_X2);
  int*   codes = (int*)(ws + OFF_CODES);
  int2*  listA = (int2*)(ws + OFF_LISTA);
  int*   listB = (int*)(ws + OFF_LISTB);
  int*   ctrs  = (int*)(ws + OFF_CTR);      // [2*l]=cntA, [2*l+1]=cntB
  float* lossp = (float*)(ws + OFF_CTR + 64);

  hipMemsetAsync(ws + OFF_CTR, 0, 68, stream);

  k_transpose_z<<<dim3((T_ + 31)/32, D_/32, B_), 256, 0, stream>>>(z, R);
  k_transpose_cb<<<dim3(K_/32, D_/32, L_), 256, 0, stream>>>(cb, cbT);
  k_y2<<<(L_ * K_)/256, 256, 0, stream>>>(cb, y2f);
  k_prep_b<<<64, 256, 0, stream>>>(cb, Bpk);
  k_x2g<<<563, 256, 0, stream>>>(R, x2);

  for (int l = 0; l < L_; ++l) {
    k_screen<<<563, 256, 0, stream>>>(
        R, Bpk + (size_t)l * 32768, y2f + (size_t)l * K_,
        codes, listA, listB, ctrs + 2*l, ctrs + 2*l + 1);
    k_fixupA<<<282, 256, 0, stream>>>(
        R, cb + (size_t)l * K_ * D_, x2, y2f + (size_t)l * K_,
        ctrs + 2*l, listA, codes);
    k_fixupB<<<563, 256, 0, stream>>>(
        R, cbT + (size_t)l * D_ * K_, x2, y2f + (size_t)l * K_,
        ctrs + 2*l + 1, listB, codes);
    k_update<<<563, 256, 0, stream>>>(
        R, cb + (size_t)l * K_ * D_, codes, x2,
        out + (size_t)N_ * D_ + (size_t)l * N_, lossp);
  }

  k_finalize_quant<<<dim3((T_ + 31)/32, D_/32, B_), 256, 0, stream>>>(z, R, out);
  k_finalize_loss<<<1, 1, 0, stream>>>(lossp, out + (size_t)N_ * D_ + (size_t)L_ * N_);
}

// Round 7
// 1539.484 us; speedup vs baseline: 2.6393x; 1.2343x over previous
//
#include <hip/hip_runtime.h>
#include <cstdint>
#include <cstddef>

#define B_ 16
#define D_ 128
#define T_ 4500
#define N_ (B_*T_)      // 72000
#define K_ 1024
#define L_ 8
#define NRB 2250        // 32-row blocks (exactly 72000/32)
#define DELTA 7.0e-5f

typedef __bf16 bf16x8 __attribute__((ext_vector_type(8)));
typedef float f32x16 __attribute__((ext_vector_type(16)));

// ---------------- helpers ----------------
// RNE f32 -> bf16 (values are tame: no NaN/Inf handling needed)
__device__ __forceinline__ unsigned short f2bf(float x) {
  unsigned u = __float_as_uint(x);
  return (unsigned short)((u + 0x7FFFu + ((u >> 16) & 1u)) >> 16);
}
// split 8 f32 into bf16 hi / bf16 lo packed as uint4 each
__device__ __forceinline__ void pack_split(const float* rn, uint4& H, uint4& L) {
  unsigned hw[8], lw[8];
#pragma unroll
  for (int i = 0; i < 8; ++i) {
    unsigned short h = f2bf(rn[i]);
    float hf = __uint_as_float(((unsigned)h) << 16);
    unsigned short lo = f2bf(__fsub_rn(rn[i], hf));
    hw[i] = h; lw[i] = lo;
  }
  H.x = hw[0] | (hw[1] << 16); H.y = hw[2] | (hw[3] << 16);
  H.z = hw[4] | (hw[5] << 16); H.w = hw[6] | (hw[7] << 16);
  L.x = lw[0] | (lw[1] << 16); L.y = lw[2] | (lw[3] << 16);
  L.z = lw[4] | (lw[5] << 16); L.w = lw[6] | (lw[7] << 16);
}

// insert packed candidate x into sorted (p1<=p2<=p3)
__device__ __forceinline__ void ins3(float& p1, float& p2, float& p3, float x) {
  p3 = fminf(p3, fmaxf(p2, x));
  p2 = fminf(p2, fmaxf(p1, x));
  p1 = fminf(p1, x);
}
// merge sorted triple (b1<=b2<=b3) into (p1<=p2<=p3)
__device__ __forceinline__ void merge3(float& p1, float& p2, float& p3,
                                       float b1, float b2, float b3) {
  ins3(p1, p2, p3, b1);
  p3 = fminf(p3, fmaxf(p2, b2));   // b2 >= b1 >= p1 already
  p2 = fminf(p2, b2);
  p3 = fminf(p3, b3);              // b3 >= b2 >= p2 already
}

// numpy pairwise_sum (n=128) of fl(x*x): 8 stride-8 sequential chains + tree
__device__ __forceinline__ float pairwise_sq_sum128(const float* __restrict__ x) {
  float r[8];
#pragma unroll
  for (int c = 0; c < 8; ++c) r[c] = __fmul_rn(x[c], x[c]);
#pragma unroll
  for (int i = 1; i < 16; ++i)
#pragma unroll
    for (int c = 0; c < 8; ++c)
      r[c] = __fadd_rn(r[c], __fmul_rn(x[8*i + c], x[8*i + c]));
  return __fadd_rn(__fadd_rn(__fadd_rn(r[0], r[1]), __fadd_rn(r[2], r[3])),
                   __fadd_rn(__fadd_rn(r[4], r[5]), __fadd_rn(r[6], r[7])));
}

__device__ __forceinline__ float tree8(const float* rc) {
  return __fadd_rn(__fadd_rn(__fadd_rn(rc[0], rc[1]), __fadd_rn(rc[2], rc[3])),
                   __fadd_rn(__fadd_rn(rc[4], rc[5]), __fadd_rn(rc[6], rc[7])));
}

// ---------------- transpose z [B][D][T] -> R [N][D] ----------------
__global__ __launch_bounds__(256)
void k_transpose_z(const float* __restrict__ z, float* __restrict__ R) {
  __shared__ float tile[32][33];
  const int t0 = blockIdx.x * 32;
  const int d0 = blockIdx.y * 32;
  const int b  = blockIdx.z;
  const int tid = threadIdx.x;
  {
    const int jj = tid & 31; const int ii0 = (tid >> 5) * 4;
#pragma unroll
    for (int r = 0; r < 4; ++r) {
      const int ii = ii0 + r;
      float v = 0.f;
      if (t0 + jj < T_) v = z[((size_t)(b*D_ + d0 + ii))*T_ + t0 + jj];
      tile[ii][jj] = v;
    }
  }
  __syncthreads();
  {
    const int ii = tid & 31; const int jj0 = (tid >> 5) * 4;
#pragma unroll
    for (int r = 0; r < 4; ++r) {
      const int jj = jj0 + r;
      if (t0 + jj < T_)
        R[((size_t)(b*T_ + t0 + jj))*D_ + d0 + ii] = tile[ii][jj];
    }
  }
}

// ---------------- transpose cb [L][K][D] -> cbT [L][D][K] ----------------
__global__ __launch_bounds__(256)
void k_transpose_cb(const float* __restrict__ cb, float* __restrict__ cbT) {
  __shared__ float tile[32][33];
  const int j0 = blockIdx.x * 32;
  const int d0 = blockIdx.y * 32;
  const int l  = blockIdx.z;
  const int tid = threadIdx.x;
  {
    const int dd = tid & 31; const int jj0 = (tid >> 5) * 4;
#pragma unroll
    for (int r = 0; r < 4; ++r)
      tile[jj0 + r][dd] = cb[((size_t)(l*K_ + j0 + jj0 + r))*D_ + d0 + dd];
  }
  __syncthreads();
  {
    const int jj = tid & 31; const int dd0 = (tid >> 5) * 4;
#pragma unroll
    for (int r = 0; r < 4; ++r)
      cbT[((size_t)(l*D_ + d0 + dd0 + r))*K_ + j0 + jj] = tile[jj][dd0 + r];
  }
}

// ---------------- per-code squared norms (numpy pairwise) ----------------
__global__ __launch_bounds__(256)
void k_y2(const float* __restrict__ cb, float* __restrict__ y2f) {
  const int row = blockIdx.x * 256 + threadIdx.x;
  if (row >= L_ * K_) return;
  y2f[row] = pairwise_sq_sum128(&cb[(size_t)row * D_]);
}

// ---------------- codebook -> fragment-ready bf16 hi/lo ----------------
// Bpk[l][colblk(32)][s(8)][p(2)][lane(64)] : uint4 (8 bf16)
// lane: col = colblk*32 + (lane&31), k = 16s + 8*(lane>>5) + 0..7
__global__ __launch_bounds__(256)
void k_prep_b(const float* __restrict__ cb, uint4* __restrict__ Bpk) {
  const int tid = threadIdx.x;
  const int gw = blockIdx.x*4 + (tid >> 6);   // 0..255
  const int l = gw >> 5, cbk = gw & 31;
  const int lane = tid & 63, l31 = lane & 31, lh = lane >> 5;
  const int col = cbk*32 + l31;
  const float* src = cb + ((size_t)l*K_ + col)*D_ + lh*8;
  uint4* dst = Bpk + (size_t)l*32768 + (size_t)cbk*1024;
#pragma unroll
  for (int s = 0; s < 8; ++s) {
    float4 va = *(const float4*)(src + s*16);
    float4 vb = *(const float4*)(src + s*16 + 4);
    float rn[8] = {va.x, va.y, va.z, va.w, vb.x, vb.y, vb.z, vb.w};
    uint4 H, L; pack_split(rn, H, L);
    dst[(2*s+0)*64 + lane] = H;
    dst[(2*s+1)*64 + lane] = L;
  }
}

// ---------------- x2 init (layer 0): numpy-pairwise sum of squares ----------------
__global__ __launch_bounds__(256)
void k_x2g(const float* __restrict__ R, float* __restrict__ x2) {
  const int tid = threadIdx.x;
  const int rowblk = blockIdx.x*4 + (tid >> 6);
  if (rowblk >= NRB) return;
  const int lane = tid & 63, l31 = lane & 31, lh = lane >> 5;
  const int row = rowblk*32 + l31;
  const float* rr = R + (size_t)row*D_ + lh*8;
  float rc[8] = {0,0,0,0,0,0,0,0};
#pragma unroll
  for (int s = 0; s < 8; ++s) {
    const float4 va = *(const float4*)(rr + s*16);
    const float4 vb = *(const float4*)(rr + s*16 + 4);
    const float rn[8] = {va.x, va.y, va.z, va.w, vb.x, vb.y, vb.z, vb.w};
#pragma unroll
    for (int c = 0; c < 8; ++c) {
      const float sq = __fmul_rn(rn[c], rn[c]);
      const float pv = __shfl_xor(sq, 32);
      rc[c] = __fadd_rn(rc[c], sq);
      rc[c] = __fadd_rn(rc[c], pv);
    }
  }
  if (lh == 0) x2[row] = tree8(rc);
}

// ---------------- MFMA screening v3 ----------------
// One 32-row block per workgroup (4 waves). Wave w scans code chunks
// [4w, 4w+4) (256 codes). Packed (u,idx) top-3 per lane -> cross-lane
// butterfly -> LDS cross-wave merge. u_j = fl(y2_j - 2*dot_j) with the
// 10-bit code index embedded in the low mantissa bits (|perturb| <= 2e-6,
// covered by DELTA margin; any mis-ordered near-tie is flagged -> fixup).
__global__ __launch_bounds__(256, 2)
void k_screen(const float* __restrict__ R, const uint4* __restrict__ Bpk_l,
              const float* __restrict__ y2l,
              int* __restrict__ codes, int2* __restrict__ listA,
              int* __restrict__ listB, int* __restrict__ cntA, int* __restrict__ cntB)
{
  __shared__ float sm[4][2][16][3];
  const int tid = threadIdx.x;
  const int w = tid >> 6;                   // wave -> chunk range
  const int lane = tid & 63, l31 = lane & 31, lh = lane >> 5;
  const int rowblk = blockIdx.x;            // grid = NRB exactly

  // load + split A fragments in-reg (k-map matches k_prep_b: k = 16s + 8*lh + c)
  uint4 ah[8], al[8];
  {
    const float* rr = R + ((size_t)rowblk*32 + l31)*D_ + lh*8;
#pragma unroll
    for (int s = 0; s < 8; ++s) {
      const float4 va = *(const float4*)(rr + s*16);
      const float4 vb = *(const float4*)(rr + s*16 + 4);
      const float rn[8] = {va.x, va.y, va.z, va.w, vb.x, vb.y, vb.z, vb.w};
      pack_split(rn, ah[s], al[s]);
    }
  }

  const float PINIT = __uint_as_float(0x7F7FFC00u);
  float p1[16], p2[16], p3[16];
#pragma unroll
  for (int r = 0; r < 16; ++r) { p1[r] = PINIT; p2[r] = PINIT; p3[r] = PINIT; }

#pragma unroll
  for (int cc = 0; cc < 4; ++cc) {
    const int ch = w*4 + cc;
    const uint4* bb = Bpk_l + (size_t)ch*2048 + lane;
    f32x16 acc0, acc1;
#pragma unroll
    for (int r = 0; r < 16; ++r) { acc0[r] = 0.f; acc1[r] = 0.f; }
#pragma unroll
    for (int s = 0; s < 8; ++s) {
      const bf16x8 Ah = __builtin_bit_cast(bf16x8, ah[s]);
      const bf16x8 Al = __builtin_bit_cast(bf16x8, al[s]);
      const bf16x8 bh0 = __builtin_bit_cast(bf16x8, bb[(2*s+0)*64]);
      const bf16x8 bl0 = __builtin_bit_cast(bf16x8, bb[(2*s+1)*64]);
      const bf16x8 bh1 = __builtin_bit_cast(bf16x8, bb[1024 + (2*s+0)*64]);
      const bf16x8 bl1 = __builtin_bit_cast(bf16x8, bb[1024 + (2*s+1)*64]);
      acc0 = __builtin_amdgcn_mfma_f32_32x32x16_bf16(Ah, bh0, acc0, 0, 0, 0);
      acc1 = __builtin_amdgcn_mfma_f32_32x32x16_bf16(Ah, bh1, acc1, 0, 0, 0);
      acc0 = __builtin_amdgcn_mfma_f32_32x32x16_bf16(Al, bh0, acc0, 0, 0, 0);
      acc1 = __builtin_amdgcn_mfma_f32_32x32x16_bf16(Al, bh1, acc1, 0, 0, 0);
      acc0 = __builtin_amdgcn_mfma_f32_32x32x16_bf16(Ah, bl0, acc0, 0, 0, 0);
      acc1 = __builtin_amdgcn_mfma_f32_32x32x16_bf16(Ah, bl1, acc1, 0, 0, 0);
    }
    const int c0 = ch * 64;
    const float y2a = y2l[c0 + l31];
    const float y2b = y2l[c0 + 32 + l31];
    const unsigned ia = (unsigned)(c0 + l31);
    const unsigned ib = (unsigned)(c0 + 32 + l31);
#pragma unroll
    for (int r = 0; r < 16; ++r) {
      const float d0 = fmaf(-2.f, acc0[r], y2a);
      const float d1 = fmaf(-2.f, acc1[r], y2b);
      const float x0 = __uint_as_float((__float_as_uint(d0) & ~1023u) | ia);
      const float x1 = __uint_as_float((__float_as_uint(d1) & ~1023u) | ib);
      ins3(p1[r], p2[r], p3[r], x0);
      ins3(p1[r], p2[r], p3[r], x1);
    }
  }

  // cross-lane butterfly within each 32-lane half
#pragma unroll
  for (int r = 0; r < 16; ++r) {
#pragma unroll
    for (int off = 1; off < 32; off <<= 1) {
      const float b1 = __shfl_xor(p1[r], off);
      const float b2 = __shfl_xor(p2[r], off);
      const float b3 = __shfl_xor(p3[r], off);
      merge3(p1[r], p2[r], p3[r], b1, b2, b3);
    }
    if (l31 == 0) {
      sm[w][lh][r][0] = p1[r];
      sm[w][lh][r][1] = p2[r];
      sm[w][lh][r][2] = p3[r];
    }
  }

  __syncthreads();

  // cross-wave merge: one thread per row (tid = (r&3) + 8*(r>>2) + 4*lh)
  if (tid < 32) {
    const int rr_ = (tid & 3) | (((tid >> 3) & 3) << 2);
    const int lhh = (tid >> 2) & 1;
    float a1 = sm[0][lhh][rr_][0], a2 = sm[0][lhh][rr_][1], a3 = sm[0][lhh][rr_][2];
#pragma unroll
    for (int ww = 1; ww < 4; ++ww)
      merge3(a1, a2, a3, sm[ww][lhh][rr_][0], sm[ww][lhh][rr_][1], sm[ww][lhh][rr_][2]);
    const int n = rowblk*32 + tid;
    const int ja = (int)(__float_as_uint(a1) & 1023u);
    codes[n] = ja;
    if (a3 - a1 <= DELTA) {                       // >=3 candidates: full scan
      const int p = atomicAdd(cntB, 1);
      listB[p] = n;
    } else if (a2 - a1 <= DELTA) {                // exactly 2 candidates
      const int p = atomicAdd(cntA, 1);
      listA[p] = make_int2(n, (int)(__float_as_uint(a2) & 1023u));
    }
  }
}

// ---------------- mode A: exact pair rescore (one lane per row) ----------------
__global__ __launch_bounds__(256)
void k_fixupA(const float* __restrict__ R, const float* __restrict__ cbl,
              const float* __restrict__ x2, const float* __restrict__ y2l,
              const int* __restrict__ cntA, const int2* __restrict__ listA,
              int* __restrict__ codes)
{
  const int C = cntA[0];
  for (int idx = blockIdx.x*256 + threadIdx.x; idx < C; idx += gridDim.x*256) {
    const int2 e = listA[idx];
    const int n = e.x;
    const int ja = codes[n], jb = e.y;
    const float* xr = &R[(size_t)n*D_];
    const float* pa = &cbl[(size_t)ja*D_];
    const float* pb = &cbl[(size_t)jb*D_];
    float s1 = 0.f, s2 = 0.f;
#pragma unroll
    for (int k = 0; k < D_; k += 4) {   // strict ascending-k BLAS chain
      const float4 x = *(const float4*)(xr + k);
      const float4 A = *(const float4*)(pa + k);
      const float4 Bv = *(const float4*)(pb + k);
      s1 = fmaf(x.x, A.x, s1);  s1 = fmaf(x.y, A.y, s1);
      s1 = fmaf(x.z, A.z, s1);  s1 = fmaf(x.w, A.w, s1);
      s2 = fmaf(x.x, Bv.x, s2); s2 = fmaf(x.y, Bv.y, s2);
      s2 = fmaf(x.z, Bv.z, s2); s2 = fmaf(x.w, Bv.w, s2);
    }
    const float x2n = x2[n];
    const float d1 = __fsub_rn(__fadd_rn(x2n, y2l[ja]), __fmul_rn(2.f, s1));
    const float d2 = __fsub_rn(__fadd_rn(x2n, y2l[jb]), __fmul_rn(2.f, s2));
    const bool take2 = (d2 < d1) || (d2 == d1 && jb < ja);
    if (take2) codes[n] = jb;
  }
}

// ---------------- mode B: exact full-scan fixup (coalesced via cbT) ----------------
__global__ __launch_bounds__(256)
void k_fixupB(const float* __restrict__ R, const float* __restrict__ cbTl,
              const float* __restrict__ x2, const float* __restrict__ y2l,
              const int* __restrict__ cntB, const int* __restrict__ listB,
              int* __restrict__ codes)
{
  __shared__ float rs[4][128];
  const int tid = threadIdx.x;
  const int wid = tid >> 6, lane = tid & 63;
  const int nw = gridDim.x * 4;
  const int gw = blockIdx.x*4 + wid;
  const int C = *cntB;
  for (int it = gw; it < C; it += nw) {
    const int n = listB[it];
    const float2 t = *(const float2*)&R[(size_t)n*D_ + lane*2];
    rs[wid][lane*2] = t.x; rs[wid][lane*2+1] = t.y;
    asm volatile("s_waitcnt lgkmcnt(0)" ::: "memory");
    const float x2n = x2[n];
    float acc[16];
#pragma unroll
    for (int q = 0; q < 16; ++q) acc[q] = 0.f;
    for (int k = 0; k < 128; ++k) {       // ascending k: exact BLAS chain per j
      const float rv = rs[wid][k];
      const float* cr = cbTl + (size_t)k*K_ + lane;
#pragma unroll
      for (int q = 0; q < 16; ++q)
        acc[q] = fmaf(rv, cr[q*64], acc[q]);   // coalesced 64-lane reads
    }
    float vb = 3.0e38f; int jb = 0;
#pragma unroll
    for (int q = 0; q < 16; ++q) {
      const int j = q*64 + lane;
      const float dv = fmaf(-2.f, acc[q], __fadd_rn(x2n, y2l[j]));
      if (dv < vb) { vb = dv; jb = j; }   // j ascends with q: ties keep lower
    }
#pragma unroll
    for (int off = 1; off < 64; off <<= 1) {
      const float bv = __shfl_xor(vb, off);
      const int   bj = __shfl_xor(jb, off);
      if (bv < vb || (bv == vb && bj < jb)) { vb = bv; jb = bj; }
    }
    if (lane == 0) codes[n] = jb;
    asm volatile("s_waitcnt lgkmcnt(0)" ::: "memory");  // rs reuse (per-wave)
  }
}

// ---------------- residual update + x2 + loss + codes out ----------------
__global__ __launch_bounds__(256)
void k_update(float* __restrict__ R, const float* __restrict__ cbl,
              const int* __restrict__ codes,
              float* __restrict__ x2, float* __restrict__ out_codes,
              float* __restrict__ lossp)
{
  const int tid = threadIdx.x;
  const int rowblk = blockIdx.x*4 + (tid >> 6);
  const int lane = tid & 63, l31 = lane & 31, lh = lane >> 5;
  const bool active = (rowblk < NRB);
  float ss = 0.f;
  if (active) {
    const int row = rowblk*32 + l31;
    const int code = codes[row];
    float* rr = R + (size_t)row*D_ + lh*8;
    const float* cr = cbl + (size_t)code*D_ + lh*8;
    float rc[8] = {0,0,0,0,0,0,0,0};
#pragma unroll
    for (int s = 0; s < 8; ++s) {
      const float4 xa = *(const float4*)(rr + s*16);
      const float4 xb = *(const float4*)(rr + s*16 + 4);
      const float4 qa = *(const float4*)(cr + s*16);
      const float4 qb = *(const float4*)(cr + s*16 + 4);
      float rn[8];
      rn[0] = __fsub_rn(xa.x, qa.x); rn[1] = __fsub_rn(xa.y, qa.y);
      rn[2] = __fsub_rn(xa.z, qa.z); rn[3] = __fsub_rn(xa.w, qa.w);
      rn[4] = __fsub_rn(xb.x, qb.x); rn[5] = __fsub_rn(xb.y, qb.y);
      rn[6] = __fsub_rn(xb.z, qb.z); rn[7] = __fsub_rn(xb.w, qb.w);
      *(float4*)(rr + s*16)     = make_float4(rn[0], rn[1], rn[2], rn[3]);
      *(float4*)(rr + s*16 + 4) = make_float4(rn[4], rn[5], rn[6], rn[7]);
#pragma unroll
      for (int c = 0; c < 8; ++c) ss = fmaf(rn[c], rn[c], ss);
#pragma unroll
      for (int c = 0; c < 8; ++c) {
        const float sq = __fmul_rn(rn[c], rn[c]);
        const float pv = __shfl_xor(sq, 32);
        rc[c] = __fadd_rn(rc[c], sq);
        rc[c] = __fadd_rn(rc[c], pv);
      }
    }
    if (lh == 0) {
      x2[row] = tree8(rc);
      out_codes[row] = (float)code;
    }
  }
#pragma unroll
  for (int off = 1; off < 64; off <<= 1) ss += __shfl_xor(ss, off);
  if (active && lane == 0) atomicAdd(lossp, ss);
}

// ---------------- finalize ----------------
__global__ __launch_bounds__(256)
void k_finalize_quant(const float* __restrict__ z, const float* __restrict__ R,
                      float* __restrict__ out) {
  __shared__ float tile[32][33];
  const int t0 = blockIdx.x * 32;
  const int d0 = blockIdx.y * 32;
  const int b  = blockIdx.z;
  const int tid = threadIdx.x;
  {
    const int ii = tid & 31; const int jj0 = (tid >> 5) * 4;
#pragma unroll
    for (int r = 0; r < 4; ++r) {
      const int jj = jj0 + r;
      tile[ii][jj] = (t0 + jj < T_) ? R[((size_t)(b*T_ + t0 + jj))*D_ + d0 + ii] : 0.f;
    }
  }
  __syncthreads();
  {
    const int jj = tid & 31; const int ii0 = (tid >> 5) * 4;
#pragma unroll
    for (int r = 0; r < 4; ++r) {
      const int ii = ii0 + r;
      if (t0 + jj < T_) {
        const size_t gi = ((size_t)(b*D_ + d0 + ii))*T_ + t0 + jj;
        out[gi] = __fsub_rn(z[gi], tile[ii][jj]);
      }
    }
  }
}

__global__ void k_finalize_loss(const float* __restrict__ lossp, float* __restrict__ out2) {
  const float lv = (float)((double)lossp[0] / (double)((size_t)N_ * D_));
  out2[0] = lv;
  out2[1] = lv;
}

// ---------------- host launch ----------------
extern "C" void kernel_launch(void* const* d_in, const int* in_sizes, int n_in,
                              void* d_out, int out_size, void* d_ws, size_t ws_size,
                              hipStream_t stream) {
  const float* z  = (const float*)d_in[0];
  const float* cb = (const float*)d_in[1];
  float* out = (float*)d_out;

  char* ws = (char*)d_ws;
  const size_t OFF_R     = 0;
  const size_t OFF_BPK   = OFF_R     + (size_t)N_ * D_ * 4;        // 36,864,000
  const size_t OFF_CBT   = OFF_BPK   + (size_t)L_ * 32768 * 16;    // 41,058,304
  const size_t OFF_Y2    = OFF_CBT   + (size_t)L_ * D_ * K_ * 4;   // 45,252,608
  const size_t OFF_X2    = OFF_Y2    + (size_t)L_ * K_ * 4;        // 45,285,376
  const size_t OFF_CODES = OFF_X2    + (size_t)N_ * 4;             // 45,573,376
  const size_t OFF_LISTA = OFF_CODES + (size_t)N_ * 4;             // 45,861,376
  const size_t OFF_LISTB = OFF_LISTA + (size_t)N_ * 8;             // 46,437,376
  const size_t OFF_CTR   = OFF_LISTB + (size_t)N_ * 4;             // 46,725,376

  float* R     = (float*)(ws + OFF_R);
  uint4* Bpk   = (uint4*)(ws + OFF_BPK);
  float* cbT   = (float*)(ws + OFF_CBT);
  float* y2f   = (float*)(ws + OFF_Y2);
  float* x2    = (float*)(ws + OFF_X2);
  int*   codes = (int*)(ws + OFF_CODES);
  int2*  listA = (int2*)(ws + OFF_LISTA);
  int*   listB = (int*)(ws + OFF_LISTB);
  int*   ctrs  = (int*)(ws + OFF_CTR);      // [2*l]=cntA, [2*l+1]=cntB
  float* lossp = (float*)(ws + OFF_CTR + 64);

  hipMemsetAsync(ws + OFF_CTR, 0, 68, stream);

  k_transpose_z<<<dim3((T_ + 31)/32, D_/32, B_), 256, 0, stream>>>(z, R);
  k_transpose_cb<<<dim3(K_/32, D_/32, L_), 256, 0, stream>>>(cb, cbT);
  k_y2<<<(L_ * K_)/256, 256, 0, stream>>>(cb, y2f);
  k_prep_b<<<64, 256, 0, stream>>>(cb, Bpk);
  k_x2g<<<563, 256, 0, stream>>>(R, x2);

  for (int l = 0; l < L_; ++l) {
    k_screen<<<NRB, 256, 0, stream>>>(
        R, Bpk + (size_t)l * 32768, y2f + (size_t)l * K_,
        codes, listA, listB, ctrs + 2*l, ctrs + 2*l + 1);
    k_fixupA<<<282, 256, 0, stream>>>(
        R, cb + (size_t)l * K_ * D_, x2, y2f + (size_t)l * K_,
        ctrs + 2*l, listA, codes);
    k_fixupB<<<563, 256, 0, stream>>>(
        R, cbT + (size_t)l * D_ * K_, x2, y2f + (size_t)l * K_,
        ctrs + 2*l + 1, listB, codes);
    k_update<<<563, 256, 0, stream>>>(
        R, cb + (size_t)l * K_ * D_, codes, x2,
        out + (size_t)N_ * D_ + (size_t)l * N_, lossp);
  }

  k_finalize_quant<<<dim3((T_ + 31)/32, D_/32, B_), 256, 0, stream>>>(z, R, out);
  k_finalize_loss<<<1, 1, 0, stream>>>(lossp, out + (size_t)N_ * D_ + (size_t)L_ * N_);
}